// Round 17
// baseline (276.123 us; speedup 1.0000x reference)
//
#include <hip/hip_runtime.h>
#include <math.h>

#define BB 2048
#define LL 64
#define EE 200
#define HH 128
#define CDIM 128
#define VV 50000
#define G3 384    // 3H
#define PEW 768   // 2*3H
#define D2H 256   // 2H
#define EPSV 1e-5f

typedef __attribute__((ext_vector_type(8))) short short8v;
typedef __attribute__((ext_vector_type(4))) float f32x4;

__device__ __forceinline__ float fast_sigmoid(float v) {
    return __builtin_amdgcn_rcpf(1.f + __expf(-v));
}
__device__ __forceinline__ float fast_tanh(float a) {
    float e = __expf(-2.f * fabsf(a));
    float m = (1.f - e) * __builtin_amdgcn_rcpf(1.f + e);
    return copysignf(m, a);
}

// ---- bf16 (raw ushort) <-> f32 helpers; storage-dtype overloads ----
__device__ __forceinline__ float bf2f(unsigned short u) {
    union { unsigned int i; float f; } c; c.i = ((unsigned int)u) << 16; return c.f;
}
__device__ __forceinline__ unsigned short f2bf(float f) {
    union { float f; unsigned int i; } c; c.f = f;
    unsigned int r = c.i + 0x7FFF + ((c.i >> 16) & 1);   // round-nearest-even
    return (unsigned short)(r >> 16);
}
__device__ __forceinline__ float ldc(const float* p) { return *p; }
__device__ __forceinline__ float ldc(const unsigned short* p) { return bf2f(*p); }
__device__ __forceinline__ void stc(float* p, float v) { *p = v; }
__device__ __forceinline__ void stc(unsigned short* p, float v) { *p = f2bf(v); }
__device__ __forceinline__ float4 ld4(const float* p) { return *(const float4*)p; }
__device__ __forceinline__ float4 ld4(const unsigned short* p) {
    ushort4 u = *(const ushort4*)p;
    return make_float4(bf2f(u.x), bf2f(u.y), bf2f(u.z), bf2f(u.w));
}

// ---------------- K0: zero the BN stats accumulators ----------------
__global__ void zero_stats_kernel(float* __restrict__ stats) {
    if (threadIdx.x < 2 * LL) stats[threadIdx.x] = 0.f;
}

// ---------------- K1: projected-embedding table (fp32, Plan A) ------
template <typename T>
__global__ __launch_bounds__(256) void pe_kernel(
    const float* __restrict__ emb,
    const float* __restrict__ Wih_f, const float* __restrict__ bih_f,
    const float* __restrict__ Wih_b, const float* __restrict__ bih_b,
    T* __restrict__ PE)
{
    __shared__ float As[8][136];
    __shared__ float Bs[8][136];
    const int mb = blockIdx.x * 128;
    const int nb = blockIdx.y * 128;
    const float* W  = (nb < G3) ? Wih_f : Wih_b;
    const float* bi = (nb < G3) ? bih_f : bih_b;
    const int nloc  = (nb < G3) ? nb : nb - G3;
    const int t  = threadIdx.x;
    const int tr = t >> 4, tc = t & 15;
    const int r  = t >> 1, q = t & 1;
    float acc[8][8] = {};
    for (int k0 = 0; k0 < EE; k0 += 8) {
        float4 av, bv;
        const int arow = mb + r;
        if (arow < VV) av = *(const float4*)(emb + (size_t)arow * EE + k0 + q * 4);
        else           av = make_float4(0.f, 0.f, 0.f, 0.f);
        bv = *(const float4*)(W + (size_t)(nloc + r) * EE + k0 + q * 4);
        __syncthreads();
        #pragma unroll
        for (int m = 0; m < 4; ++m) {
            As[q * 4 + m][r] = (&av.x)[m];
            Bs[q * 4 + m][r] = (&bv.x)[m];
        }
        __syncthreads();
        #pragma unroll
        for (int k = 0; k < 8; ++k) {
            float4 a0 = *(const float4*)&As[k][tr * 4];
            float4 a1 = *(const float4*)&As[k][64 + tr * 4];
            float4 b0 = *(const float4*)&Bs[k][tc * 4];
            float4 b1 = *(const float4*)&Bs[k][64 + tc * 4];
            float a8[8] = {a0.x,a0.y,a0.z,a0.w,a1.x,a1.y,a1.z,a1.w};
            float b8[8] = {b0.x,b0.y,b0.z,b0.w,b1.x,b1.y,b1.z,b1.w};
            #pragma unroll
            for (int i = 0; i < 8; ++i)
                #pragma unroll
                for (int j = 0; j < 8; ++j)
                    acc[i][j] = fmaf(a8[i], b8[j], acc[i][j]);
        }
    }
    #pragma unroll
    for (int i = 0; i < 8; ++i) {
        const int rl  = (i < 4) ? (tr * 4 + i) : (64 + tr * 4 + i - 4);
        const int row = mb + rl;
        if (row >= VV) continue;
        #pragma unroll
        for (int j = 0; j < 8; ++j) {
            const int cl = (j < 4) ? (tc * 4 + j) : (64 + tc * 4 + j - 4);
            stc(&PE[(size_t)row * PEW + nb + cl], acc[i][j] + bi[nloc + cl]);
        }
    }
}

// ---------------- K1b: k-major float4 repack of a [R][K] matrix -----
__global__ void transpose4_kernel(const float* __restrict__ src,
                                  float* __restrict__ dst, int R, int K) {
    int idx = blockIdx.x * blockDim.x + threadIdx.x;
    int total = R * (K >> 2);
    if (idx >= total) return;
    int k4 = idx / R, r = idx - k4 * R;
    float4 v;
    v.x = src[r * K + k4 * 4 + 0];
    v.y = src[r * K + k4 * 4 + 1];
    v.z = src[r * K + k4 * 4 + 2];
    v.w = src[r * K + k4 * 4 + 3];
    ((float4*)dst)[idx] = v;
}

// ---------------- K1c: pack Whh into MFMA B-fragments (bf16 hi/lo) --
__global__ __launch_bounds__(64) void pack_whh_kernel(
    const float* __restrict__ Whh_f, const float* __restrict__ Whh_b,
    unsigned short* __restrict__ Wpk)
{
    const int fid = blockIdx.x;
    const int l   = threadIdx.x;
    const int g   = fid % 3;
    const int kt  = (fid / 3) & 3;
    const int p   = (fid / 12) & 1;
    const int w   = (fid / 24) & 7;
    const int dir = fid / 192;
    const float* W = dir ? Whh_b : Whh_f;
    const int n  = g * HH + w * 16 + (l & 15);
    const int k0 = kt * 32 + (l >> 4) * 8;
    unsigned short* dst = Wpk + (size_t)fid * 512 + l * 8;
    #pragma unroll
    for (int r = 0; r < 8; ++r) {
        float v = W[(size_t)n * HH + k0 + r];
        unsigned short hi = f2bf(v);
        dst[r] = p ? f2bf(v - bf2f(hi)) : hi;
    }
}

// ---------------- K1d: pack Wp into MFMA B-fragments (bf16 hi/lo) ---
__global__ __launch_bounds__(64) void pack_wp_kernel(
    const float* __restrict__ Wp, unsigned short* __restrict__ WpPk)
{
    const int fid = blockIdx.x;
    const int l   = threadIdx.x;
    const int nt  = fid & 7;
    const int kt  = (fid >> 3) & 7;
    const int p   = fid >> 6;
    const int n   = nt * 16 + (l & 15);
    const int k0  = kt * 32 + (l >> 4) * 8;
    unsigned short* dst = WpPk + (size_t)fid * 512 + l * 8;
    #pragma unroll
    for (int r = 0; r < 8; ++r) {
        float v = Wp[(size_t)n * D2H + k0 + r];
        unsigned short hi = f2bf(v);
        dst[r] = p ? f2bf(v - bf2f(hi)) : hi;
    }
}

// ---------------- K1e: pack Wih into MFMA B-fragments (bf16 hi/lo) --
__global__ __launch_bounds__(64) void pack_wih_kernel(
    const float* __restrict__ Wih_f, const float* __restrict__ Wih_b,
    unsigned short* __restrict__ WihPk)
{
    const int fid = blockIdx.x;
    const int l   = threadIdx.x;
    const int nt  = fid % 48;
    const int kt  = (fid / 48) % 7;
    const int p   = fid / 336;
    const int n   = nt * 16 + (l & 15);
    const int k0  = kt * 32 + (l >> 4) * 8;
    const float* W = (n < G3) ? Wih_f : Wih_b;
    const int nl   = (n < G3) ? n : n - G3;
    unsigned short* dst = WihPk + (size_t)fid * 512 + l * 8;
    #pragma unroll
    for (int r = 0; r < 8; ++r) {
        const int k = k0 + r;
        float v = (k < EE) ? W[(size_t)nl * EE + k] : 0.f;
        unsigned short hi = f2bf(v);
        dst[r] = p ? f2bf(v - bf2f(hi)) : hi;
    }
}

// ---------------- K1': PE table via MFMA (Plan C) -------------------
// r17: M=128 rows/block + B-lo dropped. B-table L2 traffic: r16 0.54GB ->
// 0.13GB (the r15/r16 experiment pair isolated this as the bottleneck).
// B-lo drop error ~7e-4 at preact (same class as gru W-lo drop: measured 0).
__global__ __launch_bounds__(512) void pe_mfma_kernel(
    const float* __restrict__ emb,
    const unsigned short* __restrict__ WihPk,
    const float* __restrict__ bih_f, const float* __restrict__ bih_b,
    unsigned short* __restrict__ PE)
{
    __shared__ unsigned short ahi[128][264];   // 67.6 KB
    const int b0 = blockIdx.x * 128;
    const int t  = threadIdx.x;
    const int w  = t >> 6, ln = t & 63;        // 8 waves
    for (int idx = t; idx < 128 * 56; idx += 512) {
        const int r = idx / 56, q = idx - r * 56;
        const int row = b0 + r;
        float4 v = make_float4(0.f, 0.f, 0.f, 0.f);
        if (row < VV && q < 50)
            v = *(const float4*)(emb + (size_t)row * EE + q * 4);
        ushort4 h4;
        #pragma unroll
        for (int m = 0; m < 4; ++m)
            (&h4.x)[m] = f2bf((&v.x)[m]);
        *(ushort4*)&ahi[r][q * 4] = h4;
    }
    __syncthreads();
    const int sa = ln & 15, ka = (ln >> 4) * 8;
    const int rb = (ln >> 4) * 4;
    for (int it = 0; it < 3; ++it) {
        const int ntb = it * 16 + w * 2;       // this wave's first n-tile (0..47)
        f32x4 acc[8][2];
        #pragma unroll
        for (int mt = 0; mt < 8; ++mt)
            #pragma unroll
            for (int n2 = 0; n2 < 2; ++n2)
                acc[mt][n2] = (f32x4){0.f, 0.f, 0.f, 0.f};
        #pragma unroll
        for (int kt = 0; kt < 7; ++kt) {
            const unsigned short* bb = WihPk + ((size_t)(kt * 48 + ntb)) * 512 + (size_t)ln * 8;
            short8v bh0 = *(const short8v*)(bb);
            short8v bh1 = *(const short8v*)(bb + 512);
            #pragma unroll
            for (int mt = 0; mt < 8; ++mt) {
                short8v ah = *(const short8v*)&ahi[mt * 16 + sa][kt * 32 + ka];
                acc[mt][0] = __builtin_amdgcn_mfma_f32_16x16x32_bf16(ah, bh0, acc[mt][0], 0, 0, 0);
                acc[mt][1] = __builtin_amdgcn_mfma_f32_16x16x32_bf16(ah, bh1, acc[mt][1], 0, 0, 0);
            }
        }
        #pragma unroll
        for (int n2 = 0; n2 < 2; ++n2) {
            const int col = (ntb + n2) * 16 + (ln & 15);
            const float bias = (col < G3) ? bih_f[col] : bih_b[col - G3];
            #pragma unroll
            for (int mt = 0; mt < 8; ++mt) {
                #pragma unroll
                for (int reg = 0; reg < 4; ++reg) {
                    const int row = b0 + mt * 16 + rb + reg;
                    if (row < VV)
                        stc(&PE[(size_t)row * PEW + col], acc[mt][n2][reg] + bias);
                }
            }
        }
    }
}

// ---------------- K2: bidirectional GRU recurrence (MFMA, pipelined) -
// r17: single f2bf reused for hh-write and out-store; toks staged in LDS.
template <typename TPE, typename TOUT>
__global__ __launch_bounds__(512, 2) void gru_kernel(
    const int* __restrict__ xw, const int* __restrict__ lens,
    const TPE* __restrict__ PE,
    const unsigned short* __restrict__ Wpk,
    const float* __restrict__ bhh_f, const float* __restrict__ bhh_b,
    TOUT* __restrict__ out)
{
    const int dir = blockIdx.x >> 7;
    const int b0  = (blockIdx.x & 127) * 16;
    const float* bhh = dir ? bhh_b : bhh_f;
    const int t = threadIdx.x;
    const int w = t >> 6;
    const int l = t & 63;
    const int j  = w * 16 + (l & 15);
    const int sb = (l >> 4) * 4;
    const int sa = l & 15;
    const int ka = (l >> 4) * 8;
    __shared__ unsigned short hh[2][16][136];
    __shared__ int toks[16][LL];   // 4 KB

    short8v wb[4][3];   // hi-only fragments
    #pragma unroll
    for (int kt = 0; kt < 4; ++kt)
        #pragma unroll
        for (int g = 0; g < 3; ++g) {
            const size_t fid = (size_t)(dir * 192 + w * 24 + kt * 3 + g); // p=0
            wb[kt][g] = *(const short8v*)(Wpk + fid * 512 + (size_t)l * 8);
        }
    for (int i = t; i < 16 * 136; i += 512)
        ((unsigned short*)hh[0])[i] = 0;
    for (int i = t; i < 16 * LL; i += 512)
        ((int*)toks)[i] = xw[b0 * LL + i];
    const float br  = bhh[j], bz = bhh[HH + j], bn_ = bhh[2 * HH + j];
    int lens_r[4];
    #pragma unroll
    for (int r = 0; r < 4; ++r) lens_r[r] = lens[b0 + sb + r];
    const int peBase = dir * G3;
    float hprev[4] = {0.f, 0.f, 0.f, 0.f};
    __syncthreads();
    float xr[4], xz[4], xn[4];
    {
        const int lseq = dir ? (LL - 1) : 0;
        #pragma unroll
        for (int r = 0; r < 4; ++r) {
            const TPE* pp = PE + (size_t)toks[sb + r][lseq] * PEW + peBase + j;
            xr[r] = ldc(pp); xz[r] = ldc(pp + HH); xn[r] = ldc(pp + 2 * HH);
        }
    }

    for (int step = 0; step < LL; ++step) {
        const int cur = step & 1, nxt = cur ^ 1;
        const int lseq = dir ? (LL - 1 - step) : step;
        short8v ah[4];
        #pragma unroll
        for (int kt = 0; kt < 4; ++kt)
            ah[kt] = *(const short8v*)&hh[cur][sa][kt * 32 + ka];
        // unconditional clamped prefetch of x(step+1)
        float xrn[4], xzn[4], xnn[4];
        {
            int lq = dir ? (LL - 2 - step) : (step + 1);
            lq = lq < 0 ? 0 : (lq > LL - 1 ? LL - 1 : lq);
            #pragma unroll
            for (int r = 0; r < 4; ++r) {
                const TPE* pp = PE + (size_t)toks[sb + r][lq] * PEW + peBase + j;
                xrn[r] = ldc(pp); xzn[r] = ldc(pp + HH); xnn[r] = ldc(pp + 2 * HH);
            }
        }
        f32x4 aR = {0.f,0.f,0.f,0.f}, aZ = {0.f,0.f,0.f,0.f}, aN = {0.f,0.f,0.f,0.f};
        #pragma unroll
        for (int kt = 0; kt < 4; ++kt) {
            aR = __builtin_amdgcn_mfma_f32_16x16x32_bf16(ah[kt], wb[kt][0], aR, 0, 0, 0);
            aZ = __builtin_amdgcn_mfma_f32_16x16x32_bf16(ah[kt], wb[kt][1], aZ, 0, 0, 0);
            aN = __builtin_amdgcn_mfma_f32_16x16x32_bf16(ah[kt], wb[kt][2], aN, 0, 0, 0);
        }
        #pragma unroll
        for (int r = 0; r < 4; ++r) {
            const int s = sb + r;
            const float rr = fast_sigmoid(xr[r] + aR[r] + br);
            const float zz = fast_sigmoid(xz[r] + aZ[r] + bz);
            const float nn = fast_tanh(xn[r] + rr * (aN[r] + bn_));
            const float h  = (1.f - zz) * nn + zz * hprev[r];
            hprev[r] = h;
            const unsigned short us = f2bf(h);
            hh[nxt][s][j] = us;
            TOUT* po = &out[((size_t)(b0 + s) * LL + lseq) * D2H + dir * HH + j];
            if constexpr (sizeof(TOUT) == 2) {
                *(unsigned short*)po = (lseq < lens_r[r]) ? us : (unsigned short)0;
            } else {
                stc(po, (lseq < lens_r[r]) ? h : 0.f);
            }
        }
        #pragma unroll
        for (int r = 0; r < 4; ++r) {
            xr[r] = xrn[r]; xz[r] = xzn[r]; xn[r] = xnn[r];
        }
        // raw barrier: drain LDS ops only; stores/prefetch stay in flight
        __builtin_amdgcn_sched_barrier(0);
        asm volatile("s_waitcnt lgkmcnt(0)" ::: "memory");
        __builtin_amdgcn_s_barrier();
        __builtin_amdgcn_sched_barrier(0);
    }
}

// ---------------- K3: projection GEMM + BN stats (fp32, Plan A) -----
template <typename TOUT>
__global__ __launch_bounds__(256) void proj_kernel(
    const TOUT* __restrict__ out, const float* __restrict__ WpT4,
    const float* __restrict__ bp,
    float* __restrict__ proj, float* __restrict__ stats)
{
    __shared__ float outs[32][D2H];
    __shared__ float red[2][4];
    const int b0 = blockIdx.x * 32;
    const int l  = blockIdx.y;
    const int t  = threadIdx.x;
    for (int idx = t; idx < 32 * (D2H / 4); idx += 256) {
        int r = idx >> 6, c4 = idx & 63;
        float4 v = ld4(out + ((size_t)(b0 + r) * LL + l) * D2H + c4 * 4);
        *((float4*)&outs[r][c4 * 4]) = v;
    }
    __syncthreads();
    const int tr = t >> 5;
    const int tc = t & 31;
    float acc[4][4] = {};
    for (int k4 = 0; k4 < D2H / 4; ++k4) {
        float4 w[4];
        #pragma unroll
        for (int jj = 0; jj < 4; ++jj)
            w[jj] = ((const float4*)WpT4)[k4 * CDIM + tc * 4 + jj];
        #pragma unroll
        for (int i = 0; i < 4; ++i) {
            float4 a = *((const float4*)&outs[tr * 4 + i][k4 * 4]);
            #pragma unroll
            for (int jj = 0; jj < 4; ++jj) {
                acc[i][jj] = fmaf(a.x, w[jj].x, acc[i][jj]);
                acc[i][jj] = fmaf(a.y, w[jj].y, acc[i][jj]);
                acc[i][jj] = fmaf(a.z, w[jj].z, acc[i][jj]);
                acc[i][jj] = fmaf(a.w, w[jj].w, acc[i][jj]);
            }
        }
    }
    float s1 = 0.f, s2 = 0.f;
    #pragma unroll
    for (int i = 0; i < 4; ++i) {
        int b = b0 + tr * 4 + i;
        float4 pv;
        #pragma unroll
        for (int jj = 0; jj < 4; ++jj) {
            float v = acc[i][jj] + bp[tc * 4 + jj];
            (&pv.x)[jj] = v;
            s1 += v; s2 += v * v;
        }
        *((float4*)(proj + ((size_t)b * LL + l) * CDIM + tc * 4)) = pv;
    }
    #pragma unroll
    for (int off = 32; off > 0; off >>= 1) {
        s1 += __shfl_down(s1, off);
        s2 += __shfl_down(s2, off);
    }
    const int lane = t & 63, wv = t >> 6;
    if (lane == 0) { red[0][wv] = s1; red[1][wv] = s2; }
    __syncthreads();
    if (t == 0) {
        atomicAdd(&stats[l],      red[0][0] + red[0][1] + red[0][2] + red[0][3]);
        atomicAdd(&stats[LL + l], red[1][0] + red[1][1] + red[1][2] + red[1][3]);
    }
}

// ---------------- K3': projection via MFMA (bf16 out) + BN stats ----
// r17: Wp-lo dropped (table traffic halves; error ~2e-4, washed by BN).
__global__ __launch_bounds__(512) void proj_mfma_kernel(
    const unsigned short* __restrict__ out, const unsigned short* __restrict__ WpPk,
    const float* __restrict__ bp,
    float* __restrict__ proj, float* __restrict__ stats)
{
    __shared__ unsigned short outs[64][264];   // 33.8 KB
    __shared__ float red[2][8];
    const int b0 = blockIdx.x * 64;
    const int l  = blockIdx.y;
    const int t  = threadIdx.x;
    const int w  = t >> 6, ln = t & 63;        // 8 waves, wave w owns n-tile w
    for (int idx = t; idx < 64 * 32; idx += 512) {
        const int r = idx >> 5, c8 = idx & 31;
        *(short8v*)&outs[r][c8 * 8] =
            *(const short8v*)(out + ((size_t)(b0 + r) * LL + l) * D2H + c8 * 8);
    }
    __syncthreads();
    const int sa = ln & 15, ka = (ln >> 4) * 8;
    f32x4 acc[4];
    #pragma unroll
    for (int mt = 0; mt < 4; ++mt) acc[mt] = (f32x4){0.f, 0.f, 0.f, 0.f};
    #pragma unroll
    for (int kt = 0; kt < 8; ++kt) {
        short8v a[4];
        #pragma unroll
        for (int mt = 0; mt < 4; ++mt)
            a[mt] = *(const short8v*)&outs[mt * 16 + sa][kt * 32 + ka];
        const unsigned short* bbase = WpPk + ((size_t)kt * 8 + w) * 512 + (size_t)ln * 8;
        short8v bh = *(const short8v*)(bbase);
        #pragma unroll
        for (int mt = 0; mt < 4; ++mt)
            acc[mt] = __builtin_amdgcn_mfma_f32_16x16x32_bf16(a[mt], bh, acc[mt], 0, 0, 0);
    }
    float s1 = 0.f, s2 = 0.f;
    const int rb = (ln >> 4) * 4;
    const int col = w * 16 + (ln & 15);
    const float bpv = bp[col];
    #pragma unroll
    for (int mt = 0; mt < 4; ++mt) {
        #pragma unroll
        for (int reg = 0; reg < 4; ++reg) {
            const int row = b0 + mt * 16 + rb + reg;
            const float v = acc[mt][reg] + bpv;
            proj[((size_t)row * LL + l) * CDIM + col] = v;
            s1 += v; s2 += v * v;
        }
    }
    #pragma unroll
    for (int off = 32; off > 0; off >>= 1) {
        s1 += __shfl_down(s1, off);
        s2 += __shfl_down(s2, off);
    }
    if (ln == 0) { red[0][w] = s1; red[1][w] = s2; }
    __syncthreads();
    if (t == 0) {
        float r1 = 0.f, r2 = 0.f;
        #pragma unroll
        for (int i = 0; i < 8; ++i) { r1 += red[0][i]; r2 += red[1][i]; }
        atomicAdd(&stats[l], r1);
        atomicAdd(&stats[LL + l], r2);
    }
}

// ---------------- K4: BN apply + relu + dot with ctx ----------------
__global__ __launch_bounds__(256) void logits_kernel(
    const float* __restrict__ proj, const float* __restrict__ stats,
    const float* __restrict__ gamma, const float* __restrict__ beta,
    const float* __restrict__ ctx, float* __restrict__ logits)
{
    const int idx  = blockIdx.x * 4 + (threadIdx.x >> 6);
    const int lane = threadIdx.x & 63;
    const int b = idx >> 6, l = idx & 63;
    const float invN = 1.f / (float)(BB * CDIM);
    const float mean = stats[l] * invN;
    const float var  = stats[LL + l] * invN - mean * mean;
    const float inv  = rsqrtf(var + EPSV);
    const float g = gamma[l], be = beta[l];
    const float2 p = ((const float2*)(proj + ((size_t)b * LL + l) * CDIM))[lane];
    const float2 c = ((const float2*)ctx)[lane];
    float v0 = fmaxf((p.x - mean) * inv * g + be, 0.f);
    float v1 = fmaxf((p.y - mean) * inv * g + be, 0.f);
    float s = v0 * c.x + v1 * c.y;
    #pragma unroll
    for (int off = 32; off > 0; off >>= 1) s += __shfl_down(s, off);
    if (lane == 0) logits[idx] = s;
}

// ---------------- K5: softmax over L + weighted sum -----------------
template <typename TOUT>
__global__ __launch_bounds__(256) void att_out_kernel(
    const TOUT* __restrict__ out, const float* __restrict__ logits,
    float* __restrict__ y)
{
    const int b = blockIdx.x;
    const int t = threadIdx.x;
    __shared__ float att[LL];
    if (t < 64) {
        float v = logits[b * LL + t];
        float m = v;
        #pragma unroll
        for (int off = 32; off > 0; off >>= 1) m = fmaxf(m, __shfl_xor(m, off));
        float e = __expf(v - m);
        float ssum = e;
        #pragma unroll
        for (int off = 32; off > 0; off >>= 1) ssum += __shfl_xor(ssum, off);
        att[t] = e / ssum;
    }
    __syncthreads();
    float acc = 0.f;
    const TOUT* ob = out + (size_t)b * LL * D2H + t;
    #pragma unroll
    for (int l = 0; l < LL; ++l) acc = fmaf(ldc(ob + (size_t)l * D2H), att[l], acc);
    y[b * D2H + t] = acc;
}

extern "C" void kernel_launch(void* const* d_in, const int* in_sizes, int n_in,
                              void* d_out, int out_size, void* d_ws, size_t ws_size,
                              hipStream_t stream) {
    const int*   xw     = (const int*)d_in[0];
    const int*   lens   = (const int*)d_in[2];
    const float* emb    = (const float*)d_in[3];
    const float* Wih_f  = (const float*)d_in[4];
    const float* Whh_f  = (const float*)d_in[5];
    const float* bih_f  = (const float*)d_in[6];
    const float* bhh_f  = (const float*)d_in[7];
    const float* Wih_b  = (const float*)d_in[8];
    const float* Whh_b  = (const float*)d_in[9];
    const float* bih_b  = (const float*)d_in[10];
    const float* bhh_b  = (const float*)d_in[11];
    const float* Wp     = (const float*)d_in[12];
    const float* bp     = (const float*)d_in[13];
    const float* gamma  = (const float*)d_in[14];
    const float* beta   = (const float*)d_in[15];
    const float* ctx    = (const float*)d_in[16];
    float* y = (float*)d_out;

    char* base = (char*)d_ws;
    size_t off = 0;
    auto alloc = [&](size_t bytes) -> void* {
        void* p = base + off; off += (bytes + 255) & ~(size_t)255; return p;
    };
    float* WpT4  = (float*)alloc((size_t)CDIM * D2H * 4);
    float* stats = (float*)alloc(2 * LL * 4);
    float* logit = (float*)alloc((size_t)BB * LL * 4);
    unsigned short* Wpk   = (unsigned short*)alloc((size_t)384 * 512 * 2);  // Whh frags
    unsigned short* WpPk  = (unsigned short*)alloc((size_t)128 * 512 * 2);  // Wp frags
    unsigned short* WihPk = (unsigned short*)alloc((size_t)672 * 512 * 2);  // Wih frags
    const size_t extras = off;
    const size_t peB_A  = (size_t)VV * PEW * 4;
    const size_t outB_A = (size_t)BB * LL * D2H * 4;
    const size_t needA  = extras + peB_A + outB_A + 4096;
    const bool planA = ws_size >= needA;

    zero_stats_kernel<<<1, 128, 0, stream>>>(stats);
    pack_whh_kernel<<<384, 64, 0, stream>>>(Whh_f, Whh_b, Wpk);

    if (planA) {
        transpose4_kernel<<<(CDIM * D2H / 4 + 255) / 256, 256, 0, stream>>>(Wp, WpT4, CDIM, D2H);
        float* PE   = (float*)alloc(peB_A);
        float* outb = (float*)alloc(outB_A);
        float* proj = (float*)PE;   // alias: PE dead after gru_kernel
        pe_kernel<float><<<dim3((VV + 127) / 128, PEW / 128), 256, 0, stream>>>(
            emb, Wih_f, bih_f, Wih_b, bih_b, PE);
        gru_kernel<float, float><<<256, 512, 0, stream>>>(
            xw, lens, PE, Wpk, bhh_f, bhh_b, outb);
        proj_kernel<float><<<dim3(BB / 32, LL), 256, 0, stream>>>(outb, WpT4, bp, proj, stats);
        logits_kernel<<<BB * LL / 4, 256, 0, stream>>>(proj, stats, gamma, beta, ctx, logit);
        att_out_kernel<float><<<BB, 256, 0, stream>>>(outb, logit, y);
    } else {
        pack_wp_kernel<<<128, 64, 0, stream>>>(Wp, WpPk);
        pack_wih_kernel<<<672, 64, 0, stream>>>(Wih_f, Wih_b, WihPk);
        unsigned short* PE   = (unsigned short*)alloc((size_t)VV * PEW * 2);
        unsigned short* outb = (unsigned short*)alloc((size_t)BB * LL * D2H * 2);
        float* proj = (float*)PE;   // alias: 67MB fp32 <= 76.8MB bf16 PE region
        pe_mfma_kernel<<<(VV + 127) / 128, 512, 0, stream>>>(
            emb, WihPk, bih_f, bih_b, PE);
        gru_kernel<unsigned short, unsigned short><<<256, 512, 0, stream>>>(
            xw, lens, PE, Wpk, bhh_f, bhh_b, outb);
        proj_mfma_kernel<<<dim3(BB / 64, LL), 512, 0, stream>>>(outb, WpPk, bp, proj, stats);
        logits_kernel<<<BB * LL / 4, 256, 0, stream>>>(proj, stats, gamma, beta, ctx, logit);
        att_out_kernel<unsigned short><<<BB, 256, 0, stream>>>(outb, logit, y);
    }
}

// Round 18
// 244.976 us; speedup vs baseline: 1.1271x; 1.1271x over previous
//
#include <hip/hip_runtime.h>
#include <math.h>

#define BB 2048
#define LL 64
#define EE 200
#define HH 128
#define CDIM 128
#define VV 50000
#define G3 384    // 3H
#define PEW 768   // 2*3H
#define D2H 256   // 2H
#define EPSV 1e-5f

typedef __attribute__((ext_vector_type(8))) short short8v;
typedef __attribute__((ext_vector_type(4))) float f32x4;

__device__ __forceinline__ float fast_sigmoid(float v) {
    return __builtin_amdgcn_rcpf(1.f + __expf(-v));
}
__device__ __forceinline__ float fast_tanh(float a) {
    float e = __expf(-2.f * fabsf(a));
    float m = (1.f - e) * __builtin_amdgcn_rcpf(1.f + e);
    return copysignf(m, a);
}

// ---- bf16 (raw ushort) <-> f32 helpers; storage-dtype overloads ----
__device__ __forceinline__ float bf2f(unsigned short u) {
    union { unsigned int i; float f; } c; c.i = ((unsigned int)u) << 16; return c.f;
}
__device__ __forceinline__ unsigned short f2bf(float f) {
    union { float f; unsigned int i; } c; c.f = f;
    unsigned int r = c.i + 0x7FFF + ((c.i >> 16) & 1);   // round-nearest-even
    return (unsigned short)(r >> 16);
}
__device__ __forceinline__ float ldc(const float* p) { return *p; }
__device__ __forceinline__ float ldc(const unsigned short* p) { return bf2f(*p); }
__device__ __forceinline__ void stc(float* p, float v) { *p = v; }
__device__ __forceinline__ void stc(unsigned short* p, float v) { *p = f2bf(v); }
__device__ __forceinline__ float4 ld4(const float* p) { return *(const float4*)p; }
__device__ __forceinline__ float4 ld4(const unsigned short* p) {
    ushort4 u = *(const ushort4*)p;
    return make_float4(bf2f(u.x), bf2f(u.y), bf2f(u.z), bf2f(u.w));
}

// ---------------- K0: zero the BN stats accumulators ----------------
__global__ void zero_stats_kernel(float* __restrict__ stats) {
    if (threadIdx.x < 2 * LL) stats[threadIdx.x] = 0.f;
}

// ---------------- K1: projected-embedding table (fp32, Plan A) ------
template <typename T>
__global__ __launch_bounds__(256) void pe_kernel(
    const float* __restrict__ emb,
    const float* __restrict__ Wih_f, const float* __restrict__ bih_f,
    const float* __restrict__ Wih_b, const float* __restrict__ bih_b,
    T* __restrict__ PE)
{
    __shared__ float As[8][136];
    __shared__ float Bs[8][136];
    const int mb = blockIdx.x * 128;
    const int nb = blockIdx.y * 128;
    const float* W  = (nb < G3) ? Wih_f : Wih_b;
    const float* bi = (nb < G3) ? bih_f : bih_b;
    const int nloc  = (nb < G3) ? nb : nb - G3;
    const int t  = threadIdx.x;
    const int tr = t >> 4, tc = t & 15;
    const int r  = t >> 1, q = t & 1;
    float acc[8][8] = {};
    for (int k0 = 0; k0 < EE; k0 += 8) {
        float4 av, bv;
        const int arow = mb + r;
        if (arow < VV) av = *(const float4*)(emb + (size_t)arow * EE + k0 + q * 4);
        else           av = make_float4(0.f, 0.f, 0.f, 0.f);
        bv = *(const float4*)(W + (size_t)(nloc + r) * EE + k0 + q * 4);
        __syncthreads();
        #pragma unroll
        for (int m = 0; m < 4; ++m) {
            As[q * 4 + m][r] = (&av.x)[m];
            Bs[q * 4 + m][r] = (&bv.x)[m];
        }
        __syncthreads();
        #pragma unroll
        for (int k = 0; k < 8; ++k) {
            float4 a0 = *(const float4*)&As[k][tr * 4];
            float4 a1 = *(const float4*)&As[k][64 + tr * 4];
            float4 b0 = *(const float4*)&Bs[k][tc * 4];
            float4 b1 = *(const float4*)&Bs[k][64 + tc * 4];
            float a8[8] = {a0.x,a0.y,a0.z,a0.w,a1.x,a1.y,a1.z,a1.w};
            float b8[8] = {b0.x,b0.y,b0.z,b0.w,b1.x,b1.y,b1.z,b1.w};
            #pragma unroll
            for (int i = 0; i < 8; ++i)
                #pragma unroll
                for (int j = 0; j < 8; ++j)
                    acc[i][j] = fmaf(a8[i], b8[j], acc[i][j]);
        }
    }
    #pragma unroll
    for (int i = 0; i < 8; ++i) {
        const int rl  = (i < 4) ? (tr * 4 + i) : (64 + tr * 4 + i - 4);
        const int row = mb + rl;
        if (row >= VV) continue;
        #pragma unroll
        for (int j = 0; j < 8; ++j) {
            const int cl = (j < 4) ? (tc * 4 + j) : (64 + tc * 4 + j - 4);
            stc(&PE[(size_t)row * PEW + nb + cl], acc[i][j] + bi[nloc + cl]);
        }
    }
}

// ---------------- K1b: k-major float4 repack of a [R][K] matrix -----
__global__ void transpose4_kernel(const float* __restrict__ src,
                                  float* __restrict__ dst, int R, int K) {
    int idx = blockIdx.x * blockDim.x + threadIdx.x;
    int total = R * (K >> 2);
    if (idx >= total) return;
    int k4 = idx / R, r = idx - k4 * R;
    float4 v;
    v.x = src[r * K + k4 * 4 + 0];
    v.y = src[r * K + k4 * 4 + 1];
    v.z = src[r * K + k4 * 4 + 2];
    v.w = src[r * K + k4 * 4 + 3];
    ((float4*)dst)[idx] = v;
}

// ---------------- K1c: pack Whh into MFMA B-fragments (bf16 hi/lo) --
__global__ __launch_bounds__(64) void pack_whh_kernel(
    const float* __restrict__ Whh_f, const float* __restrict__ Whh_b,
    unsigned short* __restrict__ Wpk)
{
    const int fid = blockIdx.x;
    const int l   = threadIdx.x;
    const int g   = fid % 3;
    const int kt  = (fid / 3) & 3;
    const int p   = (fid / 12) & 1;
    const int w   = (fid / 24) & 7;
    const int dir = fid / 192;
    const float* W = dir ? Whh_b : Whh_f;
    const int n  = g * HH + w * 16 + (l & 15);
    const int k0 = kt * 32 + (l >> 4) * 8;
    unsigned short* dst = Wpk + (size_t)fid * 512 + l * 8;
    #pragma unroll
    for (int r = 0; r < 8; ++r) {
        float v = W[(size_t)n * HH + k0 + r];
        unsigned short hi = f2bf(v);
        dst[r] = p ? f2bf(v - bf2f(hi)) : hi;
    }
}

// ---------------- K1d: pack Wp into MFMA B-fragments (bf16 hi/lo) ---
__global__ __launch_bounds__(64) void pack_wp_kernel(
    const float* __restrict__ Wp, unsigned short* __restrict__ WpPk)
{
    const int fid = blockIdx.x;
    const int l   = threadIdx.x;
    const int nt  = fid & 7;
    const int kt  = (fid >> 3) & 7;
    const int p   = fid >> 6;
    const int n   = nt * 16 + (l & 15);
    const int k0  = kt * 32 + (l >> 4) * 8;
    unsigned short* dst = WpPk + (size_t)fid * 512 + l * 8;
    #pragma unroll
    for (int r = 0; r < 8; ++r) {
        float v = Wp[(size_t)n * D2H + k0 + r];
        unsigned short hi = f2bf(v);
        dst[r] = p ? f2bf(v - bf2f(hi)) : hi;
    }
}

// ---------------- K1e: pack Wih into MFMA B-fragments (bf16 hi/lo) --
__global__ __launch_bounds__(64) void pack_wih_kernel(
    const float* __restrict__ Wih_f, const float* __restrict__ Wih_b,
    unsigned short* __restrict__ WihPk)
{
    const int fid = blockIdx.x;
    const int l   = threadIdx.x;
    const int nt  = fid % 48;
    const int kt  = (fid / 48) % 7;
    const int p   = fid / 336;
    const int n   = nt * 16 + (l & 15);
    const int k0  = kt * 32 + (l >> 4) * 8;
    const float* W = (n < G3) ? Wih_f : Wih_b;
    const int nl   = (n < G3) ? n : n - G3;
    unsigned short* dst = WihPk + (size_t)fid * 512 + l * 8;
    #pragma unroll
    for (int r = 0; r < 8; ++r) {
        const int k = k0 + r;
        float v = (k < EE) ? W[(size_t)nl * EE + k] : 0.f;
        unsigned short hi = f2bf(v);
        dst[r] = p ? f2bf(v - bf2f(hi)) : hi;
    }
}

// ---------------- K1': PE table via MFMA (Plan C) -------------------
// r18: REVERT to M=64 (r17's M=128 spilled acc[8][2] to scratch: VGPR
// capped 128, FETCH 27->163MB, WRITE 76->190MB, 150us). Keep B-lo drop
// (table traffic 0.54 -> 0.27 GB, error ~7e-4 at preact). acc[4][2]=32
// VGPRs -> no spill.
__global__ __launch_bounds__(512) void pe_mfma_kernel(
    const float* __restrict__ emb,
    const unsigned short* __restrict__ WihPk,
    const float* __restrict__ bih_f, const float* __restrict__ bih_b,
    unsigned short* __restrict__ PE)
{
    __shared__ unsigned short ahi[64][264];   // 33.8 KB
    const int b0 = blockIdx.x * 64;
    const int t  = threadIdx.x;
    const int w  = t >> 6, ln = t & 63;       // 8 waves
    for (int idx = t; idx < 64 * 56; idx += 512) {
        const int r = idx / 56, q = idx - r * 56;
        const int row = b0 + r;
        float4 v = make_float4(0.f, 0.f, 0.f, 0.f);
        if (row < VV && q < 50)
            v = *(const float4*)(emb + (size_t)row * EE + q * 4);
        ushort4 h4;
        #pragma unroll
        for (int m = 0; m < 4; ++m)
            (&h4.x)[m] = f2bf((&v.x)[m]);
        *(ushort4*)&ahi[r][q * 4] = h4;
    }
    __syncthreads();
    const int sa = ln & 15, ka = (ln >> 4) * 8;
    const int rb = (ln >> 4) * 4;
    #pragma unroll
    for (int it = 0; it < 3; ++it) {
        const int ntb = it * 16 + w * 2;      // this wave's first n-tile (0..47)
        f32x4 acc00 = {0.f,0.f,0.f,0.f}, acc01 = {0.f,0.f,0.f,0.f};
        f32x4 acc10 = {0.f,0.f,0.f,0.f}, acc11 = {0.f,0.f,0.f,0.f};
        f32x4 acc20 = {0.f,0.f,0.f,0.f}, acc21 = {0.f,0.f,0.f,0.f};
        f32x4 acc30 = {0.f,0.f,0.f,0.f}, acc31 = {0.f,0.f,0.f,0.f};
        #pragma unroll
        for (int kt = 0; kt < 7; ++kt) {
            const unsigned short* bb = WihPk + ((size_t)(kt * 48 + ntb)) * 512 + (size_t)ln * 8;
            short8v bh0 = *(const short8v*)(bb);
            short8v bh1 = *(const short8v*)(bb + 512);
            short8v a0 = *(const short8v*)&ahi[sa][kt * 32 + ka];
            short8v a1 = *(const short8v*)&ahi[16 + sa][kt * 32 + ka];
            short8v a2 = *(const short8v*)&ahi[32 + sa][kt * 32 + ka];
            short8v a3 = *(const short8v*)&ahi[48 + sa][kt * 32 + ka];
            acc00 = __builtin_amdgcn_mfma_f32_16x16x32_bf16(a0, bh0, acc00, 0, 0, 0);
            acc01 = __builtin_amdgcn_mfma_f32_16x16x32_bf16(a0, bh1, acc01, 0, 0, 0);
            acc10 = __builtin_amdgcn_mfma_f32_16x16x32_bf16(a1, bh0, acc10, 0, 0, 0);
            acc11 = __builtin_amdgcn_mfma_f32_16x16x32_bf16(a1, bh1, acc11, 0, 0, 0);
            acc20 = __builtin_amdgcn_mfma_f32_16x16x32_bf16(a2, bh0, acc20, 0, 0, 0);
            acc21 = __builtin_amdgcn_mfma_f32_16x16x32_bf16(a2, bh1, acc21, 0, 0, 0);
            acc30 = __builtin_amdgcn_mfma_f32_16x16x32_bf16(a3, bh0, acc30, 0, 0, 0);
            acc31 = __builtin_amdgcn_mfma_f32_16x16x32_bf16(a3, bh1, acc31, 0, 0, 0);
        }
        #pragma unroll
        for (int n2 = 0; n2 < 2; ++n2) {
            const int col = (ntb + n2) * 16 + (ln & 15);
            const float bias = (col < G3) ? bih_f[col] : bih_b[col - G3];
            #pragma unroll
            for (int mt = 0; mt < 4; ++mt) {
                const f32x4 a = mt == 0 ? (n2 == 0 ? acc00 : acc01)
                              : mt == 1 ? (n2 == 0 ? acc10 : acc11)
                              : mt == 2 ? (n2 == 0 ? acc20 : acc21)
                                        : (n2 == 0 ? acc30 : acc31);
                #pragma unroll
                for (int reg = 0; reg < 4; ++reg) {
                    const int row = b0 + mt * 16 + rb + reg;
                    if (row < VV)
                        stc(&PE[(size_t)row * PEW + col], a[reg] + bias);
                }
            }
        }
    }
}

// ---------------- K2: bidirectional GRU recurrence (MFMA, pipelined) -
template <typename TPE, typename TOUT>
__global__ __launch_bounds__(512, 2) void gru_kernel(
    const int* __restrict__ xw, const int* __restrict__ lens,
    const TPE* __restrict__ PE,
    const unsigned short* __restrict__ Wpk,
    const float* __restrict__ bhh_f, const float* __restrict__ bhh_b,
    TOUT* __restrict__ out)
{
    const int dir = blockIdx.x >> 7;
    const int b0  = (blockIdx.x & 127) * 16;
    const float* bhh = dir ? bhh_b : bhh_f;
    const int t = threadIdx.x;
    const int w = t >> 6;
    const int l = t & 63;
    const int j  = w * 16 + (l & 15);
    const int sb = (l >> 4) * 4;
    const int sa = l & 15;
    const int ka = (l >> 4) * 8;
    __shared__ unsigned short hh[2][16][136];
    __shared__ int toks[16][LL];   // 4 KB

    short8v wb[4][3];   // hi-only fragments
    #pragma unroll
    for (int kt = 0; kt < 4; ++kt)
        #pragma unroll
        for (int g = 0; g < 3; ++g) {
            const size_t fid = (size_t)(dir * 192 + w * 24 + kt * 3 + g); // p=0
            wb[kt][g] = *(const short8v*)(Wpk + fid * 512 + (size_t)l * 8);
        }
    for (int i = t; i < 16 * 136; i += 512)
        ((unsigned short*)hh[0])[i] = 0;
    for (int i = t; i < 16 * LL; i += 512)
        ((int*)toks)[i] = xw[b0 * LL + i];
    const float br  = bhh[j], bz = bhh[HH + j], bn_ = bhh[2 * HH + j];
    int lens_r[4];
    #pragma unroll
    for (int r = 0; r < 4; ++r) lens_r[r] = lens[b0 + sb + r];
    const int peBase = dir * G3;
    float hprev[4] = {0.f, 0.f, 0.f, 0.f};
    __syncthreads();
    float xr[4], xz[4], xn[4];
    {
        const int lseq = dir ? (LL - 1) : 0;
        #pragma unroll
        for (int r = 0; r < 4; ++r) {
            const TPE* pp = PE + (size_t)toks[sb + r][lseq] * PEW + peBase + j;
            xr[r] = ldc(pp); xz[r] = ldc(pp + HH); xn[r] = ldc(pp + 2 * HH);
        }
    }

    for (int step = 0; step < LL; ++step) {
        const int cur = step & 1, nxt = cur ^ 1;
        const int lseq = dir ? (LL - 1 - step) : step;
        short8v ah[4];
        #pragma unroll
        for (int kt = 0; kt < 4; ++kt)
            ah[kt] = *(const short8v*)&hh[cur][sa][kt * 32 + ka];
        // unconditional clamped prefetch of x(step+1)
        float xrn[4], xzn[4], xnn[4];
        {
            int lq = dir ? (LL - 2 - step) : (step + 1);
            lq = lq < 0 ? 0 : (lq > LL - 1 ? LL - 1 : lq);
            #pragma unroll
            for (int r = 0; r < 4; ++r) {
                const TPE* pp = PE + (size_t)toks[sb + r][lq] * PEW + peBase + j;
                xrn[r] = ldc(pp); xzn[r] = ldc(pp + HH); xnn[r] = ldc(pp + 2 * HH);
            }
        }
        f32x4 aR = {0.f,0.f,0.f,0.f}, aZ = {0.f,0.f,0.f,0.f}, aN = {0.f,0.f,0.f,0.f};
        #pragma unroll
        for (int kt = 0; kt < 4; ++kt) {
            aR = __builtin_amdgcn_mfma_f32_16x16x32_bf16(ah[kt], wb[kt][0], aR, 0, 0, 0);
            aZ = __builtin_amdgcn_mfma_f32_16x16x32_bf16(ah[kt], wb[kt][1], aZ, 0, 0, 0);
            aN = __builtin_amdgcn_mfma_f32_16x16x32_bf16(ah[kt], wb[kt][2], aN, 0, 0, 0);
        }
        #pragma unroll
        for (int r = 0; r < 4; ++r) {
            const int s = sb + r;
            const float rr = fast_sigmoid(xr[r] + aR[r] + br);
            const float zz = fast_sigmoid(xz[r] + aZ[r] + bz);
            const float nn = fast_tanh(xn[r] + rr * (aN[r] + bn_));
            const float h  = (1.f - zz) * nn + zz * hprev[r];
            hprev[r] = h;
            const unsigned short us = f2bf(h);
            hh[nxt][s][j] = us;
            TOUT* po = &out[((size_t)(b0 + s) * LL + lseq) * D2H + dir * HH + j];
            if constexpr (sizeof(TOUT) == 2) {
                *(unsigned short*)po = (lseq < lens_r[r]) ? us : (unsigned short)0;
            } else {
                stc(po, (lseq < lens_r[r]) ? h : 0.f);
            }
        }
        #pragma unroll
        for (int r = 0; r < 4; ++r) {
            xr[r] = xrn[r]; xz[r] = xzn[r]; xn[r] = xnn[r];
        }
        // raw barrier: drain LDS ops only; stores/prefetch stay in flight
        __builtin_amdgcn_sched_barrier(0);
        asm volatile("s_waitcnt lgkmcnt(0)" ::: "memory");
        __builtin_amdgcn_s_barrier();
        __builtin_amdgcn_sched_barrier(0);
    }
}

// ---------------- K3: projection GEMM + BN stats (fp32, Plan A) -----
template <typename TOUT>
__global__ __launch_bounds__(256) void proj_kernel(
    const TOUT* __restrict__ out, const float* __restrict__ WpT4,
    const float* __restrict__ bp,
    float* __restrict__ proj, float* __restrict__ stats)
{
    __shared__ float outs[32][D2H];
    __shared__ float red[2][4];
    const int b0 = blockIdx.x * 32;
    const int l  = blockIdx.y;
    const int t  = threadIdx.x;
    for (int idx = t; idx < 32 * (D2H / 4); idx += 256) {
        int r = idx >> 6, c4 = idx & 63;
        float4 v = ld4(out + ((size_t)(b0 + r) * LL + l) * D2H + c4 * 4);
        *((float4*)&outs[r][c4 * 4]) = v;
    }
    __syncthreads();
    const int tr = t >> 5;
    const int tc = t & 31;
    float acc[4][4] = {};
    for (int k4 = 0; k4 < D2H / 4; ++k4) {
        float4 w[4];
        #pragma unroll
        for (int jj = 0; jj < 4; ++jj)
            w[jj] = ((const float4*)WpT4)[k4 * CDIM + tc * 4 + jj];
        #pragma unroll
        for (int i = 0; i < 4; ++i) {
            float4 a = *((const float4*)&outs[tr * 4 + i][k4 * 4]);
            #pragma unroll
            for (int jj = 0; jj < 4; ++jj) {
                acc[i][jj] = fmaf(a.x, w[jj].x, acc[i][jj]);
                acc[i][jj] = fmaf(a.y, w[jj].y, acc[i][jj]);
                acc[i][jj] = fmaf(a.z, w[jj].z, acc[i][jj]);
                acc[i][jj] = fmaf(a.w, w[jj].w, acc[i][jj]);
            }
        }
    }
    float s1 = 0.f, s2 = 0.f;
    #pragma unroll
    for (int i = 0; i < 4; ++i) {
        int b = b0 + tr * 4 + i;
        float4 pv;
        #pragma unroll
        for (int jj = 0; jj < 4; ++jj) {
            float v = acc[i][jj] + bp[tc * 4 + jj];
            (&pv.x)[jj] = v;
            s1 += v; s2 += v * v;
        }
        *((float4*)(proj + ((size_t)b * LL + l) * CDIM + tc * 4)) = pv;
    }
    #pragma unroll
    for (int off = 32; off > 0; off >>= 1) {
        s1 += __shfl_down(s1, off);
        s2 += __shfl_down(s2, off);
    }
    const int lane = t & 63, wv = t >> 6;
    if (lane == 0) { red[0][wv] = s1; red[1][wv] = s2; }
    __syncthreads();
    if (t == 0) {
        atomicAdd(&stats[l],      red[0][0] + red[0][1] + red[0][2] + red[0][3]);
        atomicAdd(&stats[LL + l], red[1][0] + red[1][1] + red[1][2] + red[1][3]);
    }
}

// ---------------- K3': projection via MFMA (bf16 out) + BN stats ----
__global__ __launch_bounds__(512) void proj_mfma_kernel(
    const unsigned short* __restrict__ out, const unsigned short* __restrict__ WpPk,
    const float* __restrict__ bp,
    float* __restrict__ proj, float* __restrict__ stats)
{
    __shared__ unsigned short outs[64][264];   // 33.8 KB
    __shared__ float red[2][8];
    const int b0 = blockIdx.x * 64;
    const int l  = blockIdx.y;
    const int t  = threadIdx.x;
    const int w  = t >> 6, ln = t & 63;        // 8 waves, wave w owns n-tile w
    for (int idx = t; idx < 64 * 32; idx += 512) {
        const int r = idx >> 5, c8 = idx & 31;
        *(short8v*)&outs[r][c8 * 8] =
            *(const short8v*)(out + ((size_t)(b0 + r) * LL + l) * D2H + c8 * 8);
    }
    __syncthreads();
    const int sa = ln & 15, ka = (ln >> 4) * 8;
    f32x4 acc[4];
    #pragma unroll
    for (int mt = 0; mt < 4; ++mt) acc[mt] = (f32x4){0.f, 0.f, 0.f, 0.f};
    #pragma unroll
    for (int kt = 0; kt < 8; ++kt) {
        short8v a[4];
        #pragma unroll
        for (int mt = 0; mt < 4; ++mt)
            a[mt] = *(const short8v*)&outs[mt * 16 + sa][kt * 32 + ka];
        const unsigned short* bbase = WpPk + ((size_t)kt * 8 + w) * 512 + (size_t)ln * 8;
        short8v bh = *(const short8v*)(bbase);
        #pragma unroll
        for (int mt = 0; mt < 4; ++mt)
            acc[mt] = __builtin_amdgcn_mfma_f32_16x16x32_bf16(a[mt], bh, acc[mt], 0, 0, 0);
    }
    float s1 = 0.f, s2 = 0.f;
    const int rb = (ln >> 4) * 4;
    const int col = w * 16 + (ln & 15);
    const float bpv = bp[col];
    #pragma unroll
    for (int mt = 0; mt < 4; ++mt) {
        #pragma unroll
        for (int reg = 0; reg < 4; ++reg) {
            const int row = b0 + mt * 16 + rb + reg;
            const float v = acc[mt][reg] + bpv;
            proj[((size_t)row * LL + l) * CDIM + col] = v;
            s1 += v; s2 += v * v;
        }
    }
    #pragma unroll
    for (int off = 32; off > 0; off >>= 1) {
        s1 += __shfl_down(s1, off);
        s2 += __shfl_down(s2, off);
    }
    if (ln == 0) { red[0][w] = s1; red[1][w] = s2; }
    __syncthreads();
    if (t == 0) {
        float r1 = 0.f, r2 = 0.f;
        #pragma unroll
        for (int i = 0; i < 8; ++i) { r1 += red[0][i]; r2 += red[1][i]; }
        atomicAdd(&stats[l], r1);
        atomicAdd(&stats[LL + l], r2);
    }
}

// ---------------- K4: BN apply + relu + dot with ctx ----------------
__global__ __launch_bounds__(256) void logits_kernel(
    const float* __restrict__ proj, const float* __restrict__ stats,
    const float* __restrict__ gamma, const float* __restrict__ beta,
    const float* __restrict__ ctx, float* __restrict__ logits)
{
    const int idx  = blockIdx.x * 4 + (threadIdx.x >> 6);
    const int lane = threadIdx.x & 63;
    const int b = idx >> 6, l = idx & 63;
    const float invN = 1.f / (float)(BB * CDIM);
    const float mean = stats[l] * invN;
    const float var  = stats[LL + l] * invN - mean * mean;
    const float inv  = rsqrtf(var + EPSV);
    const float g = gamma[l], be = beta[l];
    const float2 p = ((const float2*)(proj + ((size_t)b * LL + l) * CDIM))[lane];
    const float2 c = ((const float2*)ctx)[lane];
    float v0 = fmaxf((p.x - mean) * inv * g + be, 0.f);
    float v1 = fmaxf((p.y - mean) * inv * g + be, 0.f);
    float s = v0 * c.x + v1 * c.y;
    #pragma unroll
    for (int off = 32; off > 0; off >>= 1) s += __shfl_down(s, off);
    if (lane == 0) logits[idx] = s;
}

// ---------------- K5: softmax over L + weighted sum -----------------
template <typename TOUT>
__global__ __launch_bounds__(256) void att_out_kernel(
    const TOUT* __restrict__ out, const float* __restrict__ logits,
    float* __restrict__ y)
{
    const int b = blockIdx.x;
    const int t = threadIdx.x;
    __shared__ float att[LL];
    if (t < 64) {
        float v = logits[b * LL + t];
        float m = v;
        #pragma unroll
        for (int off = 32; off > 0; off >>= 1) m = fmaxf(m, __shfl_xor(m, off));
        float e = __expf(v - m);
        float ssum = e;
        #pragma unroll
        for (int off = 32; off > 0; off >>= 1) ssum += __shfl_xor(ssum, off);
        att[t] = e / ssum;
    }
    __syncthreads();
    float acc = 0.f;
    const TOUT* ob = out + (size_t)b * LL * D2H + t;
    #pragma unroll
    for (int l = 0; l < LL; ++l) acc = fmaf(ldc(ob + (size_t)l * D2H), att[l], acc);
    y[b * D2H + t] = acc;
}

extern "C" void kernel_launch(void* const* d_in, const int* in_sizes, int n_in,
                              void* d_out, int out_size, void* d_ws, size_t ws_size,
                              hipStream_t stream) {
    const int*   xw     = (const int*)d_in[0];
    const int*   lens   = (const int*)d_in[2];
    const float* emb    = (const float*)d_in[3];
    const float* Wih_f  = (const float*)d_in[4];
    const float* Whh_f  = (const float*)d_in[5];
    const float* bih_f  = (const float*)d_in[6];
    const float* bhh_f  = (const float*)d_in[7];
    const float* Wih_b  = (const float*)d_in[8];
    const float* Whh_b  = (const float*)d_in[9];
    const float* bih_b  = (const float*)d_in[10];
    const float* bhh_b  = (const float*)d_in[11];
    const float* Wp     = (const float*)d_in[12];
    const float* bp     = (const float*)d_in[13];
    const float* gamma  = (const float*)d_in[14];
    const float* beta   = (const float*)d_in[15];
    const float* ctx    = (const float*)d_in[16];
    float* y = (float*)d_out;

    char* base = (char*)d_ws;
    size_t off = 0;
    auto alloc = [&](size_t bytes) -> void* {
        void* p = base + off; off += (bytes + 255) & ~(size_t)255; return p;
    };
    float* WpT4  = (float*)alloc((size_t)CDIM * D2H * 4);
    float* stats = (float*)alloc(2 * LL * 4);
    float* logit = (float*)alloc((size_t)BB * LL * 4);
    unsigned short* Wpk   = (unsigned short*)alloc((size_t)384 * 512 * 2);  // Whh frags
    unsigned short* WpPk  = (unsigned short*)alloc((size_t)128 * 512 * 2);  // Wp frags
    unsigned short* WihPk = (unsigned short*)alloc((size_t)672 * 512 * 2);  // Wih frags
    const size_t extras = off;
    const size_t peB_A  = (size_t)VV * PEW * 4;
    const size_t outB_A = (size_t)BB * LL * D2H * 4;
    const size_t needA  = extras + peB_A + outB_A + 4096;
    const bool planA = ws_size >= needA;

    zero_stats_kernel<<<1, 128, 0, stream>>>(stats);
    pack_whh_kernel<<<384, 64, 0, stream>>>(Whh_f, Whh_b, Wpk);

    if (planA) {
        transpose4_kernel<<<(CDIM * D2H / 4 + 255) / 256, 256, 0, stream>>>(Wp, WpT4, CDIM, D2H);
        float* PE   = (float*)alloc(peB_A);
        float* outb = (float*)alloc(outB_A);
        float* proj = (float*)PE;   // alias: PE dead after gru_kernel
        pe_kernel<float><<<dim3((VV + 127) / 128, PEW / 128), 256, 0, stream>>>(
            emb, Wih_f, bih_f, Wih_b, bih_b, PE);
        gru_kernel<float, float><<<256, 512, 0, stream>>>(
            xw, lens, PE, Wpk, bhh_f, bhh_b, outb);
        proj_kernel<float><<<dim3(BB / 32, LL), 256, 0, stream>>>(outb, WpT4, bp, proj, stats);
        logits_kernel<<<BB * LL / 4, 256, 0, stream>>>(proj, stats, gamma, beta, ctx, logit);
        att_out_kernel<float><<<BB, 256, 0, stream>>>(outb, logit, y);
    } else {
        pack_wp_kernel<<<128, 64, 0, stream>>>(Wp, WpPk);
        pack_wih_kernel<<<672, 64, 0, stream>>>(Wih_f, Wih_b, WihPk);
        unsigned short* PE   = (unsigned short*)alloc((size_t)VV * PEW * 2);
        unsigned short* outb = (unsigned short*)alloc((size_t)BB * LL * D2H * 2);
        float* proj = (float*)PE;   // alias: 67MB fp32 <= 76.8MB bf16 PE region
        pe_mfma_kernel<<<(VV + 63) / 64, 512, 0, stream>>>(
            emb, WihPk, bih_f, bih_b, PE);
        gru_kernel<unsigned short, unsigned short><<<256, 512, 0, stream>>>(
            xw, lens, PE, Wpk, bhh_f, bhh_b, outb);
        proj_mfma_kernel<<<dim3(BB / 64, LL), 512, 0, stream>>>(outb, WpPk, bp, proj, stats);
        logits_kernel<<<BB * LL / 4, 256, 0, stream>>>(proj, stats, gamma, beta, ctx, logit);
        att_out_kernel<unsigned short><<<BB, 256, 0, stream>>>(outb, logit, y);
    }
}

// Round 20
// 212.610 us; speedup vs baseline: 1.2987x; 1.1522x over previous
//
#include <hip/hip_runtime.h>
#include <math.h>

#define BB 2048
#define LL 64
#define EE 200
#define HH 128
#define CDIM 128
#define VV 50000
#define G3 384    // 3H
#define PEW 768   // 2*3H
#define D2H 256   // 2H
#define EPSV 1e-5f

typedef __attribute__((ext_vector_type(8))) short short8v;
typedef __attribute__((ext_vector_type(4))) float f32x4;

__device__ __forceinline__ float fast_sigmoid(float v) {
    return __builtin_amdgcn_rcpf(1.f + __expf(-v));
}
__device__ __forceinline__ float fast_tanh(float a) {
    float e = __expf(-2.f * fabsf(a));
    float m = (1.f - e) * __builtin_amdgcn_rcpf(1.f + e);
    return copysignf(m, a);
}

// ---- bf16 (raw ushort) <-> f32 helpers; storage-dtype overloads ----
__device__ __forceinline__ float bf2f(unsigned short u) {
    union { unsigned int i; float f; } c; c.i = ((unsigned int)u) << 16; return c.f;
}
__device__ __forceinline__ unsigned short f2bf(float f) {
    union { float f; unsigned int i; } c; c.f = f;
    unsigned int r = c.i + 0x7FFF + ((c.i >> 16) & 1);   // round-nearest-even
    return (unsigned short)(r >> 16);
}
__device__ __forceinline__ float ldc(const float* p) { return *p; }
__device__ __forceinline__ float ldc(const unsigned short* p) { return bf2f(*p); }
__device__ __forceinline__ void stc(float* p, float v) { *p = v; }
__device__ __forceinline__ void stc(unsigned short* p, float v) { *p = f2bf(v); }
__device__ __forceinline__ float4 ld4(const float* p) { return *(const float4*)p; }
__device__ __forceinline__ float4 ld4(const unsigned short* p) {
    ushort4 u = *(const ushort4*)p;
    return make_float4(bf2f(u.x), bf2f(u.y), bf2f(u.z), bf2f(u.w));
}

// ---------------- K0: zero the BN stats accumulators ----------------
__global__ void zero_stats_kernel(float* __restrict__ stats) {
    if (threadIdx.x < 2 * LL) stats[threadIdx.x] = 0.f;
}

// ---------------- K1: projected-embedding table (fp32, Plan A) ------
template <typename T>
__global__ __launch_bounds__(256) void pe_kernel(
    const float* __restrict__ emb,
    const float* __restrict__ Wih_f, const float* __restrict__ bih_f,
    const float* __restrict__ Wih_b, const float* __restrict__ bih_b,
    T* __restrict__ PE)
{
    __shared__ float As[8][136];
    __shared__ float Bs[8][136];
    const int mb = blockIdx.x * 128;
    const int nb = blockIdx.y * 128;
    const float* W  = (nb < G3) ? Wih_f : Wih_b;
    const float* bi = (nb < G3) ? bih_f : bih_b;
    const int nloc  = (nb < G3) ? nb : nb - G3;
    const int t  = threadIdx.x;
    const int tr = t >> 4, tc = t & 15;
    const int r  = t >> 1, q = t & 1;
    float acc[8][8] = {};
    for (int k0 = 0; k0 < EE; k0 += 8) {
        float4 av, bv;
        const int arow = mb + r;
        if (arow < VV) av = *(const float4*)(emb + (size_t)arow * EE + k0 + q * 4);
        else           av = make_float4(0.f, 0.f, 0.f, 0.f);
        bv = *(const float4*)(W + (size_t)(nloc + r) * EE + k0 + q * 4);
        __syncthreads();
        #pragma unroll
        for (int m = 0; m < 4; ++m) {
            As[q * 4 + m][r] = (&av.x)[m];
            Bs[q * 4 + m][r] = (&bv.x)[m];
        }
        __syncthreads();
        #pragma unroll
        for (int k = 0; k < 8; ++k) {
            float4 a0 = *(const float4*)&As[k][tr * 4];
            float4 a1 = *(const float4*)&As[k][64 + tr * 4];
            float4 b0 = *(const float4*)&Bs[k][tc * 4];
            float4 b1 = *(const float4*)&Bs[k][64 + tc * 4];
            float a8[8] = {a0.x,a0.y,a0.z,a0.w,a1.x,a1.y,a1.z,a1.w};
            float b8[8] = {b0.x,b0.y,b0.z,b0.w,b1.x,b1.y,b1.z,b1.w};
            #pragma unroll
            for (int i = 0; i < 8; ++i)
                #pragma unroll
                for (int j = 0; j < 8; ++j)
                    acc[i][j] = fmaf(a8[i], b8[j], acc[i][j]);
        }
    }
    #pragma unroll
    for (int i = 0; i < 8; ++i) {
        const int rl  = (i < 4) ? (tr * 4 + i) : (64 + tr * 4 + i - 4);
        const int row = mb + rl;
        if (row >= VV) continue;
        #pragma unroll
        for (int j = 0; j < 8; ++j) {
            const int cl = (j < 4) ? (tc * 4 + j) : (64 + tc * 4 + j - 4);
            stc(&PE[(size_t)row * PEW + nb + cl], acc[i][j] + bi[nloc + cl]);
        }
    }
}

// ---------------- K1b: k-major float4 repack of a [R][K] matrix -----
__global__ void transpose4_kernel(const float* __restrict__ src,
                                  float* __restrict__ dst, int R, int K) {
    int idx = blockIdx.x * blockDim.x + threadIdx.x;
    int total = R * (K >> 2);
    if (idx >= total) return;
    int k4 = idx / R, r = idx - k4 * R;
    float4 v;
    v.x = src[r * K + k4 * 4 + 0];
    v.y = src[r * K + k4 * 4 + 1];
    v.z = src[r * K + k4 * 4 + 2];
    v.w = src[r * K + k4 * 4 + 3];
    ((float4*)dst)[idx] = v;
}

// ---------------- K1c: pack Whh into MFMA B-fragments (bf16 hi/lo) --
__global__ __launch_bounds__(64) void pack_whh_kernel(
    const float* __restrict__ Whh_f, const float* __restrict__ Whh_b,
    unsigned short* __restrict__ Wpk)
{
    const int fid = blockIdx.x;
    const int l   = threadIdx.x;
    const int g   = fid % 3;
    const int kt  = (fid / 3) & 3;
    const int p   = (fid / 12) & 1;
    const int w   = (fid / 24) & 7;
    const int dir = fid / 192;
    const float* W = dir ? Whh_b : Whh_f;
    const int n  = g * HH + w * 16 + (l & 15);
    const int k0 = kt * 32 + (l >> 4) * 8;
    unsigned short* dst = Wpk + (size_t)fid * 512 + l * 8;
    #pragma unroll
    for (int r = 0; r < 8; ++r) {
        float v = W[(size_t)n * HH + k0 + r];
        unsigned short hi = f2bf(v);
        dst[r] = p ? f2bf(v - bf2f(hi)) : hi;
    }
}

// ---------------- K1d: pack Wp into MFMA B-fragments (bf16 hi/lo) ---
__global__ __launch_bounds__(64) void pack_wp_kernel(
    const float* __restrict__ Wp, unsigned short* __restrict__ WpPk)
{
    const int fid = blockIdx.x;
    const int l   = threadIdx.x;
    const int nt  = fid & 7;
    const int kt  = (fid >> 3) & 7;
    const int p   = fid >> 6;
    const int n   = nt * 16 + (l & 15);
    const int k0  = kt * 32 + (l >> 4) * 8;
    unsigned short* dst = WpPk + (size_t)fid * 512 + l * 8;
    #pragma unroll
    for (int r = 0; r < 8; ++r) {
        float v = Wp[(size_t)n * D2H + k0 + r];
        unsigned short hi = f2bf(v);
        dst[r] = p ? f2bf(v - bf2f(hi)) : hi;
    }
}

// ---------------- K1e: pack Wih into MFMA B-fragments (bf16 hi/lo) --
__global__ __launch_bounds__(64) void pack_wih_kernel(
    const float* __restrict__ Wih_f, const float* __restrict__ Wih_b,
    unsigned short* __restrict__ WihPk)
{
    const int fid = blockIdx.x;
    const int l   = threadIdx.x;
    const int nt  = fid % 48;
    const int kt  = (fid / 48) % 7;
    const int p   = fid / 336;
    const int n   = nt * 16 + (l & 15);
    const int k0  = kt * 32 + (l >> 4) * 8;
    const float* W = (n < G3) ? Wih_f : Wih_b;
    const int nl   = (n < G3) ? n : n - G3;
    unsigned short* dst = WihPk + (size_t)fid * 512 + l * 8;
    #pragma unroll
    for (int r = 0; r < 8; ++r) {
        const int k = k0 + r;
        float v = (k < EE) ? W[(size_t)nl * EE + k] : 0.f;
        unsigned short hi = f2bf(v);
        dst[r] = p ? f2bf(v - bf2f(hi)) : hi;
    }
}

// ---------------- K1': PE table via MFMA (Plan C) -------------------
// r19/r20: EXACT r16 version (M=64, B hi+lo, acc[4][2]) — best measured
// (~64us). r18's B-lo drop REDUCED ILP per L2 B-load (8 MFMAs covering
// the same load latency vs 16) and regressed to 97us: in a latency-bound
// loop, overlapping work is free latency cover, not cost. M=128 spills.
__global__ __launch_bounds__(512) void pe_mfma_kernel(
    const float* __restrict__ emb,
    const unsigned short* __restrict__ WihPk,
    const float* __restrict__ bih_f, const float* __restrict__ bih_b,
    unsigned short* __restrict__ PE)
{
    __shared__ unsigned short ahi[64][264];   // 33.8 KB
    const int b0 = blockIdx.x * 64;
    const int t  = threadIdx.x;
    const int w  = t >> 6, ln = t & 63;       // 8 waves
    for (int idx = t; idx < 64 * 56; idx += 512) {
        const int r = idx / 56, q = idx - r * 56;
        const int row = b0 + r;
        float4 v = make_float4(0.f, 0.f, 0.f, 0.f);
        if (row < VV && q < 50)
            v = *(const float4*)(emb + (size_t)row * EE + q * 4);
        ushort4 h4;
        #pragma unroll
        for (int m = 0; m < 4; ++m)
            (&h4.x)[m] = f2bf((&v.x)[m]);
        *(ushort4*)&ahi[r][q * 4] = h4;
    }
    __syncthreads();
    const int sa = ln & 15, ka = (ln >> 4) * 8;
    const int rb = (ln >> 4) * 4;
    #pragma unroll
    for (int it = 0; it < 3; ++it) {
        const int ntb = it * 16 + w * 2;      // this wave's first n-tile (0..47)
        f32x4 acc[4][2];
        #pragma unroll
        for (int mt = 0; mt < 4; ++mt)
            #pragma unroll
            for (int n2 = 0; n2 < 2; ++n2)
                acc[mt][n2] = (f32x4){0.f, 0.f, 0.f, 0.f};
        #pragma unroll
        for (int kt = 0; kt < 7; ++kt) {
            short8v ah[4];
            #pragma unroll
            for (int mt = 0; mt < 4; ++mt)
                ah[mt] = *(const short8v*)&ahi[mt * 16 + sa][kt * 32 + ka];
            const unsigned short* bb = WihPk + ((size_t)(kt * 48 + ntb)) * 512 + (size_t)ln * 8;
            short8v bh0 = *(const short8v*)(bb);
            short8v bh1 = *(const short8v*)(bb + 512);
            short8v bl0 = *(const short8v*)(bb + (size_t)336 * 512);
            short8v bl1 = *(const short8v*)(bb + (size_t)336 * 512 + 512);
            #pragma unroll
            for (int mt = 0; mt < 4; ++mt) {
                acc[mt][0] = __builtin_amdgcn_mfma_f32_16x16x32_bf16(ah[mt], bh0, acc[mt][0], 0, 0, 0);
                acc[mt][0] = __builtin_amdgcn_mfma_f32_16x16x32_bf16(ah[mt], bl0, acc[mt][0], 0, 0, 0);
                acc[mt][1] = __builtin_amdgcn_mfma_f32_16x16x32_bf16(ah[mt], bh1, acc[mt][1], 0, 0, 0);
                acc[mt][1] = __builtin_amdgcn_mfma_f32_16x16x32_bf16(ah[mt], bl1, acc[mt][1], 0, 0, 0);
            }
        }
        #pragma unroll
        for (int n2 = 0; n2 < 2; ++n2) {
            const int col = (ntb + n2) * 16 + (ln & 15);
            const float bias = (col < G3) ? bih_f[col] : bih_b[col - G3];
            #pragma unroll
            for (int mt = 0; mt < 4; ++mt) {
                #pragma unroll
                for (int reg = 0; reg < 4; ++reg) {
                    const int row = b0 + mt * 16 + rb + reg;
                    if (row < VV)
                        stc(&PE[(size_t)row * PEW + col], acc[mt][n2][reg] + bias);
                }
            }
        }
    }
}

// ---------------- K2: bidirectional GRU recurrence (MFMA, pipelined) -
template <typename TPE, typename TOUT>
__global__ __launch_bounds__(512, 2) void gru_kernel(
    const int* __restrict__ xw, const int* __restrict__ lens,
    const TPE* __restrict__ PE,
    const unsigned short* __restrict__ Wpk,
    const float* __restrict__ bhh_f, const float* __restrict__ bhh_b,
    TOUT* __restrict__ out)
{
    const int dir = blockIdx.x >> 7;
    const int b0  = (blockIdx.x & 127) * 16;
    const float* bhh = dir ? bhh_b : bhh_f;
    const int t = threadIdx.x;
    const int w = t >> 6;
    const int l = t & 63;
    const int j  = w * 16 + (l & 15);
    const int sb = (l >> 4) * 4;
    const int sa = l & 15;
    const int ka = (l >> 4) * 8;
    __shared__ unsigned short hh[2][16][136];
    __shared__ int toks[16][LL];   // 4 KB

    short8v wb[4][3];   // hi-only fragments
    #pragma unroll
    for (int kt = 0; kt < 4; ++kt)
        #pragma unroll
        for (int g = 0; g < 3; ++g) {
            const size_t fid = (size_t)(dir * 192 + w * 24 + kt * 3 + g); // p=0
            wb[kt][g] = *(const short8v*)(Wpk + fid * 512 + (size_t)l * 8);
        }
    for (int i = t; i < 16 * 136; i += 512)
        ((unsigned short*)hh[0])[i] = 0;
    for (int i = t; i < 16 * LL; i += 512)
        ((int*)toks)[i] = xw[b0 * LL + i];
    const float br  = bhh[j], bz = bhh[HH + j], bn_ = bhh[2 * HH + j];
    int lens_r[4];
    #pragma unroll
    for (int r = 0; r < 4; ++r) lens_r[r] = lens[b0 + sb + r];
    const int peBase = dir * G3;
    float hprev[4] = {0.f, 0.f, 0.f, 0.f};
    __syncthreads();
    float xr[4], xz[4], xn[4];
    {
        const int lseq = dir ? (LL - 1) : 0;
        #pragma unroll
        for (int r = 0; r < 4; ++r) {
            const TPE* pp = PE + (size_t)toks[sb + r][lseq] * PEW + peBase + j;
            xr[r] = ldc(pp); xz[r] = ldc(pp + HH); xn[r] = ldc(pp + 2 * HH);
        }
    }

    for (int step = 0; step < LL; ++step) {
        const int cur = step & 1, nxt = cur ^ 1;
        const int lseq = dir ? (LL - 1 - step) : step;
        short8v ah[4];
        #pragma unroll
        for (int kt = 0; kt < 4; ++kt)
            ah[kt] = *(const short8v*)&hh[cur][sa][kt * 32 + ka];
        // unconditional clamped prefetch of x(step+1)
        float xrn[4], xzn[4], xnn[4];
        {
            int lq = dir ? (LL - 2 - step) : (step + 1);
            lq = lq < 0 ? 0 : (lq > LL - 1 ? LL - 1 : lq);
            #pragma unroll
            for (int r = 0; r < 4; ++r) {
                const TPE* pp = PE + (size_t)toks[sb + r][lq] * PEW + peBase + j;
                xrn[r] = ldc(pp); xzn[r] = ldc(pp + HH); xnn[r] = ldc(pp + 2 * HH);
            }
        }
        f32x4 aR = {0.f,0.f,0.f,0.f}, aZ = {0.f,0.f,0.f,0.f}, aN = {0.f,0.f,0.f,0.f};
        #pragma unroll
        for (int kt = 0; kt < 4; ++kt) {
            aR = __builtin_amdgcn_mfma_f32_16x16x32_bf16(ah[kt], wb[kt][0], aR, 0, 0, 0);
            aZ = __builtin_amdgcn_mfma_f32_16x16x32_bf16(ah[kt], wb[kt][1], aZ, 0, 0, 0);
            aN = __builtin_amdgcn_mfma_f32_16x16x32_bf16(ah[kt], wb[kt][2], aN, 0, 0, 0);
        }
        #pragma unroll
        for (int r = 0; r < 4; ++r) {
            const int s = sb + r;
            const float rr = fast_sigmoid(xr[r] + aR[r] + br);
            const float zz = fast_sigmoid(xz[r] + aZ[r] + bz);
            const float nn = fast_tanh(xn[r] + rr * (aN[r] + bn_));
            const float h  = (1.f - zz) * nn + zz * hprev[r];
            hprev[r] = h;
            const unsigned short us = f2bf(h);
            hh[nxt][s][j] = us;
            TOUT* po = &out[((size_t)(b0 + s) * LL + lseq) * D2H + dir * HH + j];
            if constexpr (sizeof(TOUT) == 2) {
                *(unsigned short*)po = (lseq < lens_r[r]) ? us : (unsigned short)0;
            } else {
                stc(po, (lseq < lens_r[r]) ? h : 0.f);
            }
        }
        #pragma unroll
        for (int r = 0; r < 4; ++r) {
            xr[r] = xrn[r]; xz[r] = xzn[r]; xn[r] = xnn[r];
        }
        // raw barrier: drain LDS ops only; stores/prefetch stay in flight
        __builtin_amdgcn_sched_barrier(0);
        asm volatile("s_waitcnt lgkmcnt(0)" ::: "memory");
        __builtin_amdgcn_s_barrier();
        __builtin_amdgcn_sched_barrier(0);
    }
}

// ---------------- K3: projection GEMM + BN stats (fp32, Plan A) -----
template <typename TOUT>
__global__ __launch_bounds__(256) void proj_kernel(
    const TOUT* __restrict__ out, const float* __restrict__ WpT4,
    const float* __restrict__ bp,
    float* __restrict__ proj, float* __restrict__ stats)
{
    __shared__ float outs[32][D2H];
    __shared__ float red[2][4];
    const int b0 = blockIdx.x * 32;
    const int l  = blockIdx.y;
    const int t  = threadIdx.x;
    for (int idx = t; idx < 32 * (D2H / 4); idx += 256) {
        int r = idx >> 6, c4 = idx & 63;
        float4 v = ld4(out + ((size_t)(b0 + r) * LL + l) * D2H + c4 * 4);
        *((float4*)&outs[r][c4 * 4]) = v;
    }
    __syncthreads();
    const int tr = t >> 5;
    const int tc = t & 31;
    float acc[4][4] = {};
    for (int k4 = 0; k4 < D2H / 4; ++k4) {
        float4 w[4];
        #pragma unroll
        for (int jj = 0; jj < 4; ++jj)
            w[jj] = ((const float4*)WpT4)[k4 * CDIM + tc * 4 + jj];
        #pragma unroll
        for (int i = 0; i < 4; ++i) {
            float4 a = *((const float4*)&outs[tr * 4 + i][k4 * 4]);
            #pragma unroll
            for (int jj = 0; jj < 4; ++jj) {
                acc[i][jj] = fmaf(a.x, w[jj].x, acc[i][jj]);
                acc[i][jj] = fmaf(a.y, w[jj].y, acc[i][jj]);
                acc[i][jj] = fmaf(a.z, w[jj].z, acc[i][jj]);
                acc[i][jj] = fmaf(a.w, w[jj].w, acc[i][jj]);
            }
        }
    }
    float s1 = 0.f, s2 = 0.f;
    #pragma unroll
    for (int i = 0; i < 4; ++i) {
        int b = b0 + tr * 4 + i;
        float4 pv;
        #pragma unroll
        for (int jj = 0; jj < 4; ++jj) {
            float v = acc[i][jj] + bp[tc * 4 + jj];
            (&pv.x)[jj] = v;
            s1 += v; s2 += v * v;
        }
        *((float4*)(proj + ((size_t)b * LL + l) * CDIM + tc * 4)) = pv;
    }
    #pragma unroll
    for (int off = 32; off > 0; off >>= 1) {
        s1 += __shfl_down(s1, off);
        s2 += __shfl_down(s2, off);
    }
    const int lane = t & 63, wv = t >> 6;
    if (lane == 0) { red[0][wv] = s1; red[1][wv] = s2; }
    __syncthreads();
    if (t == 0) {
        atomicAdd(&stats[l],      red[0][0] + red[0][1] + red[0][2] + red[0][3]);
        atomicAdd(&stats[LL + l], red[1][0] + red[1][1] + red[1][2] + red[1][3]);
    }
}

// ---------------- K3': projection via MFMA (bf16 out) + BN stats ----
__global__ __launch_bounds__(512) void proj_mfma_kernel(
    const unsigned short* __restrict__ out, const unsigned short* __restrict__ WpPk,
    const float* __restrict__ bp,
    float* __restrict__ proj, float* __restrict__ stats)
{
    __shared__ unsigned short outs[64][264];   // 33.8 KB
    __shared__ float red[2][8];
    const int b0 = blockIdx.x * 64;
    const int l  = blockIdx.y;
    const int t  = threadIdx.x;
    const int w  = t >> 6, ln = t & 63;        // 8 waves, wave w owns n-tile w
    for (int idx = t; idx < 64 * 32; idx += 512) {
        const int r = idx >> 5, c8 = idx & 31;
        *(short8v*)&outs[r][c8 * 8] =
            *(const short8v*)(out + ((size_t)(b0 + r) * LL + l) * D2H + c8 * 8);
    }
    __syncthreads();
    const int sa = ln & 15, ka = (ln >> 4) * 8;
    f32x4 acc[4];
    #pragma unroll
    for (int mt = 0; mt < 4; ++mt) acc[mt] = (f32x4){0.f, 0.f, 0.f, 0.f};
    #pragma unroll
    for (int kt = 0; kt < 8; ++kt) {
        short8v a[4];
        #pragma unroll
        for (int mt = 0; mt < 4; ++mt)
            a[mt] = *(const short8v*)&outs[mt * 16 + sa][kt * 32 + ka];
        const unsigned short* bbase = WpPk + ((size_t)kt * 8 + w) * 512 + (size_t)ln * 8;
        short8v bh = *(const short8v*)(bbase);
        #pragma unroll
        for (int mt = 0; mt < 4; ++mt)
            acc[mt] = __builtin_amdgcn_mfma_f32_16x16x32_bf16(a[mt], bh, acc[mt], 0, 0, 0);
    }
    float s1 = 0.f, s2 = 0.f;
    const int rb = (ln >> 4) * 4;
    const int col = w * 16 + (ln & 15);
    const float bpv = bp[col];
    #pragma unroll
    for (int mt = 0; mt < 4; ++mt) {
        #pragma unroll
        for (int reg = 0; reg < 4; ++reg) {
            const int row = b0 + mt * 16 + rb + reg;
            const float v = acc[mt][reg] + bpv;
            proj[((size_t)row * LL + l) * CDIM + col] = v;
            s1 += v; s2 += v * v;
        }
    }
    #pragma unroll
    for (int off = 32; off > 0; off >>= 1) {
        s1 += __shfl_down(s1, off);
        s2 += __shfl_down(s2, off);
    }
    if (ln == 0) { red[0][w] = s1; red[1][w] = s2; }
    __syncthreads();
    if (t == 0) {
        float r1 = 0.f, r2 = 0.f;
        #pragma unroll
        for (int i = 0; i < 8; ++i) { r1 += red[0][i]; r2 += red[1][i]; }
        atomicAdd(&stats[l], r1);
        atomicAdd(&stats[LL + l], r2);
    }
}

// ---------------- K4: BN apply + relu + dot with ctx ----------------
__global__ __launch_bounds__(256) void logits_kernel(
    const float* __restrict__ proj, const float* __restrict__ stats,
    const float* __restrict__ gamma, const float* __restrict__ beta,
    const float* __restrict__ ctx, float* __restrict__ logits)
{
    const int idx  = blockIdx.x * 4 + (threadIdx.x >> 6);
    const int lane = threadIdx.x & 63;
    const int b = idx >> 6, l = idx & 63;
    const float invN = 1.f / (float)(BB * CDIM);
    const float mean = stats[l] * invN;
    const float var  = stats[LL + l] * invN - mean * mean;
    const float inv  = rsqrtf(var + EPSV);
    const float g = gamma[l], be = beta[l];
    const float2 p = ((const float2*)(proj + ((size_t)b * LL + l) * CDIM))[lane];
    const float2 c = ((const float2*)ctx)[lane];
    float v0 = fmaxf((p.x - mean) * inv * g + be, 0.f);
    float v1 = fmaxf((p.y - mean) * inv * g + be, 0.f);
    float s = v0 * c.x + v1 * c.y;
    #pragma unroll
    for (int off = 32; off > 0; off >>= 1) s += __shfl_down(s, off);
    if (lane == 0) logits[idx] = s;
}

// ---------------- K5: softmax over L + weighted sum -----------------
template <typename TOUT>
__global__ __launch_bounds__(256) void att_out_kernel(
    const TOUT* __restrict__ out, const float* __restrict__ logits,
    float* __restrict__ y)
{
    const int b = blockIdx.x;
    const int t = threadIdx.x;
    __shared__ float att[LL];
    if (t < 64) {
        float v = logits[b * LL + t];
        float m = v;
        #pragma unroll
        for (int off = 32; off > 0; off >>= 1) m = fmaxf(m, __shfl_xor(m, off));
        float e = __expf(v - m);
        float ssum = e;
        #pragma unroll
        for (int off = 32; off > 0; off >>= 1) ssum += __shfl_xor(ssum, off);
        att[t] = e / ssum;
    }
    __syncthreads();
    float acc = 0.f;
    const TOUT* ob = out + (size_t)b * LL * D2H + t;
    #pragma unroll
    for (int l = 0; l < LL; ++l) acc = fmaf(ldc(ob + (size_t)l * D2H), att[l], acc);
    y[b * D2H + t] = acc;
}

extern "C" void kernel_launch(void* const* d_in, const int* in_sizes, int n_in,
                              void* d_out, int out_size, void* d_ws, size_t ws_size,
                              hipStream_t stream) {
    const int*   xw     = (const int*)d_in[0];
    const int*   lens   = (const int*)d_in[2];
    const float* emb    = (const float*)d_in[3];
    const float* Wih_f  = (const float*)d_in[4];
    const float* Whh_f  = (const float*)d_in[5];
    const float* bih_f  = (const float*)d_in[6];
    const float* bhh_f  = (const float*)d_in[7];
    const float* Wih_b  = (const float*)d_in[8];
    const float* Whh_b  = (const float*)d_in[9];
    const float* bih_b  = (const float*)d_in[10];
    const float* bhh_b  = (const float*)d_in[11];
    const float* Wp     = (const float*)d_in[12];
    const float* bp     = (const float*)d_in[13];
    const float* gamma  = (const float*)d_in[14];
    const float* beta   = (const float*)d_in[15];
    const float* ctx    = (const float*)d_in[16];
    float* y = (float*)d_out;

    char* base = (char*)d_ws;
    size_t off = 0;
    auto alloc = [&](size_t bytes) -> void* {
        void* p = base + off; off += (bytes + 255) & ~(size_t)255; return p;
    };
    float* WpT4  = (float*)alloc((size_t)CDIM * D2H * 4);
    float* stats = (float*)alloc(2 * LL * 4);
    float* logit = (float*)alloc((size_t)BB * LL * 4);
    unsigned short* Wpk   = (unsigned short*)alloc((size_t)384 * 512 * 2);  // Whh frags
    unsigned short* WpPk  = (unsigned short*)alloc((size_t)128 * 512 * 2);  // Wp frags
    unsigned short* WihPk = (unsigned short*)alloc((size_t)672 * 512 * 2);  // Wih frags
    const size_t extras = off;
    const size_t peB_A  = (size_t)VV * PEW * 4;
    const size_t outB_A = (size_t)BB * LL * D2H * 4;
    const size_t needA  = extras + peB_A + outB_A + 4096;
    const bool planA = ws_size >= needA;

    zero_stats_kernel<<<1, 128, 0, stream>>>(stats);
    pack_whh_kernel<<<384, 64, 0, stream>>>(Whh_f, Whh_b, Wpk);

    if (planA) {
        transpose4_kernel<<<(CDIM * D2H / 4 + 255) / 256, 256, 0, stream>>>(Wp, WpT4, CDIM, D2H);
        float* PE   = (float*)alloc(peB_A);
        float* outb = (float*)alloc(outB_A);
        float* proj = (float*)PE;   // alias: PE dead after gru_kernel
        pe_kernel<float><<<dim3((VV + 127) / 128, PEW / 128), 256, 0, stream>>>(
            emb, Wih_f, bih_f, Wih_b, bih_b, PE);
        gru_kernel<float, float><<<256, 512, 0, stream>>>(
            xw, lens, PE, Wpk, bhh_f, bhh_b, outb);
        proj_kernel<float><<<dim3(BB / 32, LL), 256, 0, stream>>>(outb, WpT4, bp, proj, stats);
        logits_kernel<<<BB * LL / 4, 256, 0, stream>>>(proj, stats, gamma, beta, ctx, logit);
        att_out_kernel<float><<<BB, 256, 0, stream>>>(outb, logit, y);
    } else {
        pack_wp_kernel<<<128, 64, 0, stream>>>(Wp, WpPk);
        pack_wih_kernel<<<672, 64, 0, stream>>>(Wih_f, Wih_b, WihPk);
        unsigned short* PE   = (unsigned short*)alloc((size_t)VV * PEW * 2);
        unsigned short* outb = (unsigned short*)alloc((size_t)BB * LL * D2H * 2);
        float* proj = (float*)PE;   // alias: 67MB fp32 <= 76.8MB bf16 PE region
        pe_mfma_kernel<<<(VV + 63) / 64, 512, 0, stream>>>(
            emb, WihPk, bih_f, bih_b, PE);
        gru_kernel<unsigned short, unsigned short><<<256, 512, 0, stream>>>(
            xw, lens, PE, Wpk, bhh_f, bhh_b, outb);
        proj_mfma_kernel<<<dim3(BB / 64, LL), 512, 0, stream>>>(outb, WpPk, bp, proj, stats);
        logits_kernel<<<BB * LL / 4, 256, 0, stream>>>(proj, stats, gamma, beta, ctx, logit);
        att_out_kernel<unsigned short><<<BB, 256, 0, stream>>>(outb, logit, y);
    }
}

// Round 22
// 207.369 us; speedup vs baseline: 1.3316x; 1.0253x over previous
//
#include <hip/hip_runtime.h>
#include <math.h>

#define BB 2048
#define LL 64
#define EE 200
#define HH 128
#define CDIM 128
#define VV 50000
#define G3 384    // 3H
#define PEW 768   // 2*3H
#define D2H 256   // 2H
#define EPSV 1e-5f

typedef __attribute__((ext_vector_type(8))) short short8v;
typedef __attribute__((ext_vector_type(4))) float f32x4;

__device__ __forceinline__ float fast_sigmoid(float v) {
    return __builtin_amdgcn_rcpf(1.f + __expf(-v));
}
__device__ __forceinline__ float fast_tanh(float a) {
    float e = __expf(-2.f * fabsf(a));
    float m = (1.f - e) * __builtin_amdgcn_rcpf(1.f + e);
    return copysignf(m, a);
}

// ---- bf16 (raw ushort) <-> f32 helpers; storage-dtype overloads ----
__device__ __forceinline__ float bf2f(unsigned short u) {
    union { unsigned int i; float f; } c; c.i = ((unsigned int)u) << 16; return c.f;
}
__device__ __forceinline__ unsigned short f2bf(float f) {
    union { float f; unsigned int i; } c; c.f = f;
    unsigned int r = c.i + 0x7FFF + ((c.i >> 16) & 1);   // round-nearest-even
    return (unsigned short)(r >> 16);
}
__device__ __forceinline__ float ldc(const float* p) { return *p; }
__device__ __forceinline__ float ldc(const unsigned short* p) { return bf2f(*p); }
__device__ __forceinline__ void stc(float* p, float v) { *p = v; }
__device__ __forceinline__ void stc(unsigned short* p, float v) { *p = f2bf(v); }
__device__ __forceinline__ float4 ld4(const float* p) { return *(const float4*)p; }
__device__ __forceinline__ float4 ld4(const unsigned short* p) {
    ushort4 u = *(const ushort4*)p;
    return make_float4(bf2f(u.x), bf2f(u.y), bf2f(u.z), bf2f(u.w));
}

// ---------------- K0: zero the BN stats accumulators ----------------
__global__ void zero_stats_kernel(float* __restrict__ stats) {
    if (threadIdx.x < 2 * LL) stats[threadIdx.x] = 0.f;
}

// ---------------- K1: projected-embedding table (fp32, Plan A) ------
template <typename T>
__global__ __launch_bounds__(256) void pe_kernel(
    const float* __restrict__ emb,
    const float* __restrict__ Wih_f, const float* __restrict__ bih_f,
    const float* __restrict__ Wih_b, const float* __restrict__ bih_b,
    T* __restrict__ PE)
{
    __shared__ float As[8][136];
    __shared__ float Bs[8][136];
    const int mb = blockIdx.x * 128;
    const int nb = blockIdx.y * 128;
    const float* W  = (nb < G3) ? Wih_f : Wih_b;
    const float* bi = (nb < G3) ? bih_f : bih_b;
    const int nloc  = (nb < G3) ? nb : nb - G3;
    const int t  = threadIdx.x;
    const int tr = t >> 4, tc = t & 15;
    const int r  = t >> 1, q = t & 1;
    float acc[8][8] = {};
    for (int k0 = 0; k0 < EE; k0 += 8) {
        float4 av, bv;
        const int arow = mb + r;
        if (arow < VV) av = *(const float4*)(emb + (size_t)arow * EE + k0 + q * 4);
        else           av = make_float4(0.f, 0.f, 0.f, 0.f);
        bv = *(const float4*)(W + (size_t)(nloc + r) * EE + k0 + q * 4);
        __syncthreads();
        #pragma unroll
        for (int m = 0; m < 4; ++m) {
            As[q * 4 + m][r] = (&av.x)[m];
            Bs[q * 4 + m][r] = (&bv.x)[m];
        }
        __syncthreads();
        #pragma unroll
        for (int k = 0; k < 8; ++k) {
            float4 a0 = *(const float4*)&As[k][tr * 4];
            float4 a1 = *(const float4*)&As[k][64 + tr * 4];
            float4 b0 = *(const float4*)&Bs[k][tc * 4];
            float4 b1 = *(const float4*)&Bs[k][64 + tc * 4];
            float a8[8] = {a0.x,a0.y,a0.z,a0.w,a1.x,a1.y,a1.z,a1.w};
            float b8[8] = {b0.x,b0.y,b0.z,b0.w,b1.x,b1.y,b1.z,b1.w};
            #pragma unroll
            for (int i = 0; i < 8; ++i)
                #pragma unroll
                for (int j = 0; j < 8; ++j)
                    acc[i][j] = fmaf(a8[i], b8[j], acc[i][j]);
        }
    }
    #pragma unroll
    for (int i = 0; i < 8; ++i) {
        const int rl  = (i < 4) ? (tr * 4 + i) : (64 + tr * 4 + i - 4);
        const int row = mb + rl;
        if (row >= VV) continue;
        #pragma unroll
        for (int j = 0; j < 8; ++j) {
            const int cl = (j < 4) ? (tc * 4 + j) : (64 + tc * 4 + j - 4);
            stc(&PE[(size_t)row * PEW + nb + cl], acc[i][j] + bi[nloc + cl]);
        }
    }
}

// ---------------- K1b: k-major float4 repack of a [R][K] matrix -----
__global__ void transpose4_kernel(const float* __restrict__ src,
                                  float* __restrict__ dst, int R, int K) {
    int idx = blockIdx.x * blockDim.x + threadIdx.x;
    int total = R * (K >> 2);
    if (idx >= total) return;
    int k4 = idx / R, r = idx - k4 * R;
    float4 v;
    v.x = src[r * K + k4 * 4 + 0];
    v.y = src[r * K + k4 * 4 + 1];
    v.z = src[r * K + k4 * 4 + 2];
    v.w = src[r * K + k4 * 4 + 3];
    ((float4*)dst)[idx] = v;
}

// ---------------- K1c: pack Whh into MFMA B-fragments (bf16 hi/lo) --
__global__ __launch_bounds__(64) void pack_whh_kernel(
    const float* __restrict__ Whh_f, const float* __restrict__ Whh_b,
    unsigned short* __restrict__ Wpk)
{
    const int fid = blockIdx.x;
    const int l   = threadIdx.x;
    const int g   = fid % 3;
    const int kt  = (fid / 3) & 3;
    const int p   = (fid / 12) & 1;
    const int w   = (fid / 24) & 7;
    const int dir = fid / 192;
    const float* W = dir ? Whh_b : Whh_f;
    const int n  = g * HH + w * 16 + (l & 15);
    const int k0 = kt * 32 + (l >> 4) * 8;
    unsigned short* dst = Wpk + (size_t)fid * 512 + l * 8;
    #pragma unroll
    for (int r = 0; r < 8; ++r) {
        float v = W[(size_t)n * HH + k0 + r];
        unsigned short hi = f2bf(v);
        dst[r] = p ? f2bf(v - bf2f(hi)) : hi;
    }
}

// ---------------- K1d: pack Wp into MFMA B-fragments (bf16 hi/lo) ---
__global__ __launch_bounds__(64) void pack_wp_kernel(
    const float* __restrict__ Wp, unsigned short* __restrict__ WpPk)
{
    const int fid = blockIdx.x;
    const int l   = threadIdx.x;
    const int nt  = fid & 7;
    const int kt  = (fid >> 3) & 7;
    const int p   = fid >> 6;
    const int n   = nt * 16 + (l & 15);
    const int k0  = kt * 32 + (l >> 4) * 8;
    unsigned short* dst = WpPk + (size_t)fid * 512 + l * 8;
    #pragma unroll
    for (int r = 0; r < 8; ++r) {
        float v = Wp[(size_t)n * D2H + k0 + r];
        unsigned short hi = f2bf(v);
        dst[r] = p ? f2bf(v - bf2f(hi)) : hi;
    }
}

// ---------------- K1e: pack Wih into MFMA B-fragments (bf16 hi/lo) --
__global__ __launch_bounds__(64) void pack_wih_kernel(
    const float* __restrict__ Wih_f, const float* __restrict__ Wih_b,
    unsigned short* __restrict__ WihPk)
{
    const int fid = blockIdx.x;
    const int l   = threadIdx.x;
    const int nt  = fid % 48;
    const int kt  = (fid / 48) % 7;
    const int p   = fid / 336;
    const int n   = nt * 16 + (l & 15);
    const int k0  = kt * 32 + (l >> 4) * 8;
    const float* W = (n < G3) ? Wih_f : Wih_b;
    const int nl   = (n < G3) ? n : n - G3;
    unsigned short* dst = WihPk + (size_t)fid * 512 + l * 8;
    #pragma unroll
    for (int r = 0; r < 8; ++r) {
        const int k = k0 + r;
        float v = (k < EE) ? W[(size_t)nl * EE + k] : 0.f;
        unsigned short hi = f2bf(v);
        dst[r] = p ? f2bf(v - bf2f(hi)) : hi;
    }
}

// ---------------- K1': PE table via MFMA (Plan C) -------------------
// r16-optimal config (M=64, B hi+lo, acc[4][2]): measured ~64us. Mapped
// space: M=32→85 (table-traffic), M=64 hi-only→97 (ILP-starved),
// M=128→150 (VGPR spill).
__global__ __launch_bounds__(512) void pe_mfma_kernel(
    const float* __restrict__ emb,
    const unsigned short* __restrict__ WihPk,
    const float* __restrict__ bih_f, const float* __restrict__ bih_b,
    unsigned short* __restrict__ PE)
{
    __shared__ unsigned short ahi[64][264];   // 33.8 KB
    const int b0 = blockIdx.x * 64;
    const int t  = threadIdx.x;
    const int w  = t >> 6, ln = t & 63;       // 8 waves
    for (int idx = t; idx < 64 * 56; idx += 512) {
        const int r = idx / 56, q = idx - r * 56;
        const int row = b0 + r;
        float4 v = make_float4(0.f, 0.f, 0.f, 0.f);
        if (row < VV && q < 50)
            v = *(const float4*)(emb + (size_t)row * EE + q * 4);
        ushort4 h4;
        #pragma unroll
        for (int m = 0; m < 4; ++m)
            (&h4.x)[m] = f2bf((&v.x)[m]);
        *(ushort4*)&ahi[r][q * 4] = h4;
    }
    __syncthreads();
    const int sa = ln & 15, ka = (ln >> 4) * 8;
    const int rb = (ln >> 4) * 4;
    #pragma unroll
    for (int it = 0; it < 3; ++it) {
        const int ntb = it * 16 + w * 2;      // this wave's first n-tile (0..47)
        f32x4 acc[4][2];
        #pragma unroll
        for (int mt = 0; mt < 4; ++mt)
            #pragma unroll
            for (int n2 = 0; n2 < 2; ++n2)
                acc[mt][n2] = (f32x4){0.f, 0.f, 0.f, 0.f};
        #pragma unroll
        for (int kt = 0; kt < 7; ++kt) {
            short8v ah[4];
            #pragma unroll
            for (int mt = 0; mt < 4; ++mt)
                ah[mt] = *(const short8v*)&ahi[mt * 16 + sa][kt * 32 + ka];
            const unsigned short* bb = WihPk + ((size_t)(kt * 48 + ntb)) * 512 + (size_t)ln * 8;
            short8v bh0 = *(const short8v*)(bb);
            short8v bh1 = *(const short8v*)(bb + 512);
            short8v bl0 = *(const short8v*)(bb + (size_t)336 * 512);
            short8v bl1 = *(const short8v*)(bb + (size_t)336 * 512 + 512);
            #pragma unroll
            for (int mt = 0; mt < 4; ++mt) {
                acc[mt][0] = __builtin_amdgcn_mfma_f32_16x16x32_bf16(ah[mt], bh0, acc[mt][0], 0, 0, 0);
                acc[mt][0] = __builtin_amdgcn_mfma_f32_16x16x32_bf16(ah[mt], bl0, acc[mt][0], 0, 0, 0);
                acc[mt][1] = __builtin_amdgcn_mfma_f32_16x16x32_bf16(ah[mt], bh1, acc[mt][1], 0, 0, 0);
                acc[mt][1] = __builtin_amdgcn_mfma_f32_16x16x32_bf16(ah[mt], bl1, acc[mt][1], 0, 0, 0);
            }
        }
        #pragma unroll
        for (int n2 = 0; n2 < 2; ++n2) {
            const int col = (ntb + n2) * 16 + (ln & 15);
            const float bias = (col < G3) ? bih_f[col] : bih_b[col - G3];
            #pragma unroll
            for (int mt = 0; mt < 4; ++mt) {
                #pragma unroll
                for (int reg = 0; reg < 4; ++reg) {
                    const int row = b0 + mt * 16 + rb + reg;
                    if (row < VV)
                        stc(&PE[(size_t)row * PEW + col], acc[mt][n2][reg] + bias);
                }
            }
        }
    }
}

// ---------------- K2: bidirectional GRU recurrence (MFMA, pipelined) -
// EXACT r16 gru (76.7us measured). r17's toks-LDS staging put a ~120cy
// LDS read into the prefetch addressing chain (replacing an L1-resident
// 4KB/block global load) and regressed to 82.5us.
template <typename TPE, typename TOUT>
__global__ __launch_bounds__(512, 2) void gru_kernel(
    const int* __restrict__ xw, const int* __restrict__ lens,
    const TPE* __restrict__ PE,
    const unsigned short* __restrict__ Wpk,
    const float* __restrict__ bhh_f, const float* __restrict__ bhh_b,
    TOUT* __restrict__ out)
{
    const int dir = blockIdx.x >> 7;
    const int b0  = (blockIdx.x & 127) * 16;
    const float* bhh = dir ? bhh_b : bhh_f;
    const int t = threadIdx.x;
    const int w = t >> 6;
    const int l = t & 63;
    const int j  = w * 16 + (l & 15);
    const int sb = (l >> 4) * 4;
    const int sa = l & 15;
    const int ka = (l >> 4) * 8;
    __shared__ unsigned short hh[2][16][136];

    short8v wb[4][3];   // hi-only fragments
    #pragma unroll
    for (int kt = 0; kt < 4; ++kt)
        #pragma unroll
        for (int g = 0; g < 3; ++g) {
            const size_t fid = (size_t)(dir * 192 + w * 24 + kt * 3 + g); // p=0
            wb[kt][g] = *(const short8v*)(Wpk + fid * 512 + (size_t)l * 8);
        }
    for (int i = t; i < 16 * 136; i += 512)
        ((unsigned short*)hh[0])[i] = 0;
    const float br  = bhh[j], bz = bhh[HH + j], bn_ = bhh[2 * HH + j];
    int lens_r[4];
    #pragma unroll
    for (int r = 0; r < 4; ++r) lens_r[r] = lens[b0 + sb + r];
    const int peBase = dir * G3;
    float hprev[4] = {0.f, 0.f, 0.f, 0.f};
    float xr[4], xz[4], xn[4];
    {
        const int lseq = dir ? (LL - 1) : 0;
        #pragma unroll
        for (int r = 0; r < 4; ++r) {
            const int tok = xw[(b0 + sb + r) * LL + lseq];
            const TPE* pp = PE + (size_t)tok * PEW + peBase + j;
            xr[r] = ldc(pp); xz[r] = ldc(pp + HH); xn[r] = ldc(pp + 2 * HH);
        }
    }
    __syncthreads();

    for (int step = 0; step < LL; ++step) {
        const int cur = step & 1, nxt = cur ^ 1;
        const int lseq = dir ? (LL - 1 - step) : step;
        short8v ah[4];
        #pragma unroll
        for (int kt = 0; kt < 4; ++kt)
            ah[kt] = *(const short8v*)&hh[cur][sa][kt * 32 + ka];
        // unconditional clamped prefetch of x(step+1)
        float xrn[4], xzn[4], xnn[4];
        {
            int lq = dir ? (LL - 2 - step) : (step + 1);
            lq = lq < 0 ? 0 : (lq > LL - 1 ? LL - 1 : lq);
            #pragma unroll
            for (int r = 0; r < 4; ++r) {
                const int tok = xw[(b0 + sb + r) * LL + lq];
                const TPE* pp = PE + (size_t)tok * PEW + peBase + j;
                xrn[r] = ldc(pp); xzn[r] = ldc(pp + HH); xnn[r] = ldc(pp + 2 * HH);
            }
        }
        f32x4 aR = {0.f,0.f,0.f,0.f}, aZ = {0.f,0.f,0.f,0.f}, aN = {0.f,0.f,0.f,0.f};
        #pragma unroll
        for (int kt = 0; kt < 4; ++kt) {
            aR = __builtin_amdgcn_mfma_f32_16x16x32_bf16(ah[kt], wb[kt][0], aR, 0, 0, 0);
            aZ = __builtin_amdgcn_mfma_f32_16x16x32_bf16(ah[kt], wb[kt][1], aZ, 0, 0, 0);
            aN = __builtin_amdgcn_mfma_f32_16x16x32_bf16(ah[kt], wb[kt][2], aN, 0, 0, 0);
        }
        #pragma unroll
        for (int r = 0; r < 4; ++r) {
            const int s = sb + r;
            const float rr = fast_sigmoid(xr[r] + aR[r] + br);
            const float zz = fast_sigmoid(xz[r] + aZ[r] + bz);
            const float nn = fast_tanh(xn[r] + rr * (aN[r] + bn_));
            const float h  = (1.f - zz) * nn + zz * hprev[r];
            hprev[r] = h;
            hh[nxt][s][j] = f2bf(h);
            stc(&out[((size_t)(b0 + s) * LL + lseq) * D2H + dir * HH + j],
                (lseq < lens_r[r]) ? h : 0.f);
        }
        #pragma unroll
        for (int r = 0; r < 4; ++r) {
            xr[r] = xrn[r]; xz[r] = xzn[r]; xn[r] = xnn[r];
        }
        // raw barrier: drain LDS ops only; stores/prefetch stay in flight
        __builtin_amdgcn_sched_barrier(0);
        asm volatile("s_waitcnt lgkmcnt(0)" ::: "memory");
        __builtin_amdgcn_s_barrier();
        __builtin_amdgcn_sched_barrier(0);
    }
}

// ---------------- K3: projection GEMM + BN stats (fp32, Plan A) -----
template <typename TOUT>
__global__ __launch_bounds__(256) void proj_kernel(
    const TOUT* __restrict__ out, const float* __restrict__ WpT4,
    const float* __restrict__ bp,
    float* __restrict__ proj, float* __restrict__ stats)
{
    __shared__ float outs[32][D2H];
    __shared__ float red[2][4];
    const int b0 = blockIdx.x * 32;
    const int l  = blockIdx.y;
    const int t  = threadIdx.x;
    for (int idx = t; idx < 32 * (D2H / 4); idx += 256) {
        int r = idx >> 6, c4 = idx & 63;
        float4 v = ld4(out + ((size_t)(b0 + r) * LL + l) * D2H + c4 * 4);
        *((float4*)&outs[r][c4 * 4]) = v;
    }
    __syncthreads();
    const int tr = t >> 5;
    const int tc = t & 31;
    float acc[4][4] = {};
    for (int k4 = 0; k4 < D2H / 4; ++k4) {
        float4 w[4];
        #pragma unroll
        for (int jj = 0; jj < 4; ++jj)
            w[jj] = ((const float4*)WpT4)[k4 * CDIM + tc * 4 + jj];
        #pragma unroll
        for (int i = 0; i < 4; ++i) {
            float4 a = *((const float4*)&outs[tr * 4 + i][k4 * 4]);
            #pragma unroll
            for (int jj = 0; jj < 4; ++jj) {
                acc[i][jj] = fmaf(a.x, w[jj].x, acc[i][jj]);
                acc[i][jj] = fmaf(a.y, w[jj].y, acc[i][jj]);
                acc[i][jj] = fmaf(a.z, w[jj].z, acc[i][jj]);
                acc[i][jj] = fmaf(a.w, w[jj].w, acc[i][jj]);
            }
        }
    }
    float s1 = 0.f, s2 = 0.f;
    #pragma unroll
    for (int i = 0; i < 4; ++i) {
        int b = b0 + tr * 4 + i;
        float4 pv;
        #pragma unroll
        for (int jj = 0; jj < 4; ++jj) {
            float v = acc[i][jj] + bp[tc * 4 + jj];
            (&pv.x)[jj] = v;
            s1 += v; s2 += v * v;
        }
        *((float4*)(proj + ((size_t)b * LL + l) * CDIM + tc * 4)) = pv;
    }
    #pragma unroll
    for (int off = 32; off > 0; off >>= 1) {
        s1 += __shfl_down(s1, off);
        s2 += __shfl_down(s2, off);
    }
    const int lane = t & 63, wv = t >> 6;
    if (lane == 0) { red[0][wv] = s1; red[1][wv] = s2; }
    __syncthreads();
    if (t == 0) {
        atomicAdd(&stats[l],      red[0][0] + red[0][1] + red[0][2] + red[0][3]);
        atomicAdd(&stats[LL + l], red[1][0] + red[1][1] + red[1][2] + red[1][3]);
    }
}

// ---------------- K3': projection via MFMA (bf16 out) + BN stats ----
__global__ __launch_bounds__(512) void proj_mfma_kernel(
    const unsigned short* __restrict__ out, const unsigned short* __restrict__ WpPk,
    const float* __restrict__ bp,
    float* __restrict__ proj, float* __restrict__ stats)
{
    __shared__ unsigned short outs[64][264];   // 33.8 KB
    __shared__ float red[2][8];
    const int b0 = blockIdx.x * 64;
    const int l  = blockIdx.y;
    const int t  = threadIdx.x;
    const int w  = t >> 6, ln = t & 63;        // 8 waves, wave w owns n-tile w
    for (int idx = t; idx < 64 * 32; idx += 512) {
        const int r = idx >> 5, c8 = idx & 31;
        *(short8v*)&outs[r][c8 * 8] =
            *(const short8v*)(out + ((size_t)(b0 + r) * LL + l) * D2H + c8 * 8);
    }
    __syncthreads();
    const int sa = ln & 15, ka = (ln >> 4) * 8;
    f32x4 acc[4];
    #pragma unroll
    for (int mt = 0; mt < 4; ++mt) acc[mt] = (f32x4){0.f, 0.f, 0.f, 0.f};
    #pragma unroll
    for (int kt = 0; kt < 8; ++kt) {
        short8v a[4];
        #pragma unroll
        for (int mt = 0; mt < 4; ++mt)
            a[mt] = *(const short8v*)&outs[mt * 16 + sa][kt * 32 + ka];
        const unsigned short* bbase = WpPk + ((size_t)kt * 8 + w) * 512 + (size_t)ln * 8;
        short8v bh = *(const short8v*)(bbase);
        #pragma unroll
        for (int mt = 0; mt < 4; ++mt)
            acc[mt] = __builtin_amdgcn_mfma_f32_16x16x32_bf16(a[mt], bh, acc[mt], 0, 0, 0);
    }
    float s1 = 0.f, s2 = 0.f;
    const int rb = (ln >> 4) * 4;
    const int col = w * 16 + (ln & 15);
    const float bpv = bp[col];
    #pragma unroll
    for (int mt = 0; mt < 4; ++mt) {
        #pragma unroll
        for (int reg = 0; reg < 4; ++reg) {
            const int row = b0 + mt * 16 + rb + reg;
            const float v = acc[mt][reg] + bpv;
            proj[((size_t)row * LL + l) * CDIM + col] = v;
            s1 += v; s2 += v * v;
        }
    }
    #pragma unroll
    for (int off = 32; off > 0; off >>= 1) {
        s1 += __shfl_down(s1, off);
        s2 += __shfl_down(s2, off);
    }
    if (ln == 0) { red[0][w] = s1; red[1][w] = s2; }
    __syncthreads();
    if (t == 0) {
        float r1 = 0.f, r2 = 0.f;
        #pragma unroll
        for (int i = 0; i < 8; ++i) { r1 += red[0][i]; r2 += red[1][i]; }
        atomicAdd(&stats[l], r1);
        atomicAdd(&stats[LL + l], r2);
    }
}

// ---------------- K4: BN apply + relu + dot with ctx ----------------
__global__ __launch_bounds__(256) void logits_kernel(
    const float* __restrict__ proj, const float* __restrict__ stats,
    const float* __restrict__ gamma, const float* __restrict__ beta,
    const float* __restrict__ ctx, float* __restrict__ logits)
{
    const int idx  = blockIdx.x * 4 + (threadIdx.x >> 6);
    const int lane = threadIdx.x & 63;
    const int b = idx >> 6, l = idx & 63;
    const float invN = 1.f / (float)(BB * CDIM);
    const float mean = stats[l] * invN;
    const float var  = stats[LL + l] * invN - mean * mean;
    const float inv  = rsqrtf(var + EPSV);
    const float g = gamma[l], be = beta[l];
    const float2 p = ((const float2*)(proj + ((size_t)b * LL + l) * CDIM))[lane];
    const float2 c = ((const float2*)ctx)[lane];
    float v0 = fmaxf((p.x - mean) * inv * g + be, 0.f);
    float v1 = fmaxf((p.y - mean) * inv * g + be, 0.f);
    float s = v0 * c.x + v1 * c.y;
    #pragma unroll
    for (int off = 32; off > 0; off >>= 1) s += __shfl_down(s, off);
    if (lane == 0) logits[idx] = s;
}

// ---------------- K5: softmax over L + weighted sum -----------------
template <typename TOUT>
__global__ __launch_bounds__(256) void att_out_kernel(
    const TOUT* __restrict__ out, const float* __restrict__ logits,
    float* __restrict__ y)
{
    const int b = blockIdx.x;
    const int t = threadIdx.x;
    __shared__ float att[LL];
    if (t < 64) {
        float v = logits[b * LL + t];
        float m = v;
        #pragma unroll
        for (int off = 32; off > 0; off >>= 1) m = fmaxf(m, __shfl_xor(m, off));
        float e = __expf(v - m);
        float ssum = e;
        #pragma unroll
        for (int off = 32; off > 0; off >>= 1) ssum += __shfl_xor(ssum, off);
        att[t] = e / ssum;
    }
    __syncthreads();
    float acc = 0.f;
    const TOUT* ob = out + (size_t)b * LL * D2H + t;
    #pragma unroll
    for (int l = 0; l < LL; ++l) acc = fmaf(ldc(ob + (size_t)l * D2H), att[l], acc);
    y[b * D2H + t] = acc;
}

extern "C" void kernel_launch(void* const* d_in, const int* in_sizes, int n_in,
                              void* d_out, int out_size, void* d_ws, size_t ws_size,
                              hipStream_t stream) {
    const int*   xw     = (const int*)d_in[0];
    const int*   lens   = (const int*)d_in[2];
    const float* emb    = (const float*)d_in[3];
    const float* Wih_f  = (const float*)d_in[4];
    const float* Whh_f  = (const float*)d_in[5];
    const float* bih_f  = (const float*)d_in[6];
    const float* bhh_f  = (const float*)d_in[7];
    const float* Wih_b  = (const float*)d_in[8];
    const float* Whh_b  = (const float*)d_in[9];
    const float* bih_b  = (const float*)d_in[10];
    const float* bhh_b  = (const float*)d_in[11];
    const float* Wp     = (const float*)d_in[12];
    const float* bp     = (const float*)d_in[13];
    const float* gamma  = (const float*)d_in[14];
    const float* beta   = (const float*)d_in[15];
    const float* ctx    = (const float*)d_in[16];
    float* y = (float*)d_out;

    char* base = (char*)d_ws;
    size_t off = 0;
    auto alloc = [&](size_t bytes) -> void* {
        void* p = base + off; off += (bytes + 255) & ~(size_t)255; return p;
    };
    float* WpT4  = (float*)alloc((size_t)CDIM * D2H * 4);
    float* stats = (float*)alloc(2 * LL * 4);
    float* logit = (float*)alloc((size_t)BB * LL * 4);
    unsigned short* Wpk   = (unsigned short*)alloc((size_t)384 * 512 * 2);  // Whh frags
    unsigned short* WpPk  = (unsigned short*)alloc((size_t)128 * 512 * 2);  // Wp frags
    unsigned short* WihPk = (unsigned short*)alloc((size_t)672 * 512 * 2);  // Wih frags
    const size_t extras = off;
    const size_t peB_A  = (size_t)VV * PEW * 4;
    const size_t outB_A = (size_t)BB * LL * D2H * 4;
    const size_t needA  = extras + peB_A + outB_A + 4096;
    const bool planA = ws_size >= needA;

    zero_stats_kernel<<<1, 128, 0, stream>>>(stats);
    pack_whh_kernel<<<384, 64, 0, stream>>>(Whh_f, Whh_b, Wpk);

    if (planA) {
        transpose4_kernel<<<(CDIM * D2H / 4 + 255) / 256, 256, 0, stream>>>(Wp, WpT4, CDIM, D2H);
        float* PE   = (float*)alloc(peB_A);
        float* outb = (float*)alloc(outB_A);
        float* proj = (float*)PE;   // alias: PE dead after gru_kernel
        pe_kernel<float><<<dim3((VV + 127) / 128, PEW / 128), 256, 0, stream>>>(
            emb, Wih_f, bih_f, Wih_b, bih_b, PE);
        gru_kernel<float, float><<<256, 512, 0, stream>>>(
            xw, lens, PE, Wpk, bhh_f, bhh_b, outb);
        proj_kernel<float><<<dim3(BB / 32, LL), 256, 0, stream>>>(outb, WpT4, bp, proj, stats);
        logits_kernel<<<BB * LL / 4, 256, 0, stream>>>(proj, stats, gamma, beta, ctx, logit);
        att_out_kernel<float><<<BB, 256, 0, stream>>>(outb, logit, y);
    } else {
        pack_wp_kernel<<<128, 64, 0, stream>>>(Wp, WpPk);
        pack_wih_kernel<<<672, 64, 0, stream>>>(Wih_f, Wih_b, WihPk);
        unsigned short* PE   = (unsigned short*)alloc((size_t)VV * PEW * 2);
        unsigned short* outb = (unsigned short*)alloc((size_t)BB * LL * D2H * 2);
        float* proj = (float*)PE;   // alias: 67MB fp32 <= 76.8MB bf16 PE region
        pe_mfma_kernel<<<(VV + 63) / 64, 512, 0, stream>>>(
            emb, WihPk, bih_f, bih_b, PE);
        gru_kernel<unsigned short, unsigned short><<<256, 512, 0, stream>>>(
            xw, lens, PE, Wpk, bhh_f, bhh_b, outb);
        proj_mfma_kernel<<<dim3(BB / 64, LL), 512, 0, stream>>>(outb, WpPk, bp, proj, stats);
        logits_kernel<<<BB * LL / 4, 256, 0, stream>>>(proj, stats, gamma, beta, ctx, logit);
        att_out_kernel<unsigned short><<<BB, 256, 0, stream>>>(outb, logit, y);
    }
}

// Round 23
// 201.697 us; speedup vs baseline: 1.3690x; 1.0281x over previous
//
#include <hip/hip_runtime.h>
#include <math.h>

#define BB 2048
#define LL 64
#define EE 200
#define HH 128
#define CDIM 128
#define VV 50000
#define G3 384    // 3H
#define PEW 768   // 2*3H
#define D2H 256   // 2H
#define EPSV 1e-5f

typedef __attribute__((ext_vector_type(8))) short short8v;
typedef __attribute__((ext_vector_type(4))) float f32x4;

__device__ __forceinline__ float fast_sigmoid(float v) {
    return __builtin_amdgcn_rcpf(1.f + __expf(-v));
}
__device__ __forceinline__ float fast_tanh(float a) {
    float e = __expf(-2.f * fabsf(a));
    float m = (1.f - e) * __builtin_amdgcn_rcpf(1.f + e);
    return copysignf(m, a);
}

// ---- bf16 (raw ushort) <-> f32 helpers; storage-dtype overloads ----
__device__ __forceinline__ float bf2f(unsigned short u) {
    union { unsigned int i; float f; } c; c.i = ((unsigned int)u) << 16; return c.f;
}
__device__ __forceinline__ unsigned short f2bf(float f) {
    union { float f; unsigned int i; } c; c.f = f;
    unsigned int r = c.i + 0x7FFF + ((c.i >> 16) & 1);   // round-nearest-even
    return (unsigned short)(r >> 16);
}
__device__ __forceinline__ float ldc(const float* p) { return *p; }
__device__ __forceinline__ float ldc(const unsigned short* p) { return bf2f(*p); }
__device__ __forceinline__ void stc(float* p, float v) { *p = v; }
__device__ __forceinline__ void stc(unsigned short* p, float v) { *p = f2bf(v); }
__device__ __forceinline__ float4 ld4(const float* p) { return *(const float4*)p; }
__device__ __forceinline__ float4 ld4(const unsigned short* p) {
    ushort4 u = *(const ushort4*)p;
    return make_float4(bf2f(u.x), bf2f(u.y), bf2f(u.z), bf2f(u.w));
}

// ---------------- K0: zero the BN stats accumulators ----------------
__global__ void zero_stats_kernel(float* __restrict__ stats) {
    if (threadIdx.x < 2 * LL) stats[threadIdx.x] = 0.f;
}

// ---------------- K1: projected-embedding table (fp32, Plan A) ------
template <typename T>
__global__ __launch_bounds__(256) void pe_kernel(
    const float* __restrict__ emb,
    const float* __restrict__ Wih_f, const float* __restrict__ bih_f,
    const float* __restrict__ Wih_b, const float* __restrict__ bih_b,
    T* __restrict__ PE)
{
    __shared__ float As[8][136];
    __shared__ float Bs[8][136];
    const int mb = blockIdx.x * 128;
    const int nb = blockIdx.y * 128;
    const float* W  = (nb < G3) ? Wih_f : Wih_b;
    const float* bi = (nb < G3) ? bih_f : bih_b;
    const int nloc  = (nb < G3) ? nb : nb - G3;
    const int t  = threadIdx.x;
    const int tr = t >> 4, tc = t & 15;
    const int r  = t >> 1, q = t & 1;
    float acc[8][8] = {};
    for (int k0 = 0; k0 < EE; k0 += 8) {
        float4 av, bv;
        const int arow = mb + r;
        if (arow < VV) av = *(const float4*)(emb + (size_t)arow * EE + k0 + q * 4);
        else           av = make_float4(0.f, 0.f, 0.f, 0.f);
        bv = *(const float4*)(W + (size_t)(nloc + r) * EE + k0 + q * 4);
        __syncthreads();
        #pragma unroll
        for (int m = 0; m < 4; ++m) {
            As[q * 4 + m][r] = (&av.x)[m];
            Bs[q * 4 + m][r] = (&bv.x)[m];
        }
        __syncthreads();
        #pragma unroll
        for (int k = 0; k < 8; ++k) {
            float4 a0 = *(const float4*)&As[k][tr * 4];
            float4 a1 = *(const float4*)&As[k][64 + tr * 4];
            float4 b0 = *(const float4*)&Bs[k][tc * 4];
            float4 b1 = *(const float4*)&Bs[k][64 + tc * 4];
            float a8[8] = {a0.x,a0.y,a0.z,a0.w,a1.x,a1.y,a1.z,a1.w};
            float b8[8] = {b0.x,b0.y,b0.z,b0.w,b1.x,b1.y,b1.z,b1.w};
            #pragma unroll
            for (int i = 0; i < 8; ++i)
                #pragma unroll
                for (int j = 0; j < 8; ++j)
                    acc[i][j] = fmaf(a8[i], b8[j], acc[i][j]);
        }
    }
    #pragma unroll
    for (int i = 0; i < 8; ++i) {
        const int rl  = (i < 4) ? (tr * 4 + i) : (64 + tr * 4 + i - 4);
        const int row = mb + rl;
        if (row >= VV) continue;
        #pragma unroll
        for (int j = 0; j < 8; ++j) {
            const int cl = (j < 4) ? (tc * 4 + j) : (64 + tc * 4 + j - 4);
            stc(&PE[(size_t)row * PEW + nb + cl], acc[i][j] + bi[nloc + cl]);
        }
    }
}

// ---------------- K1b: k-major float4 repack of a [R][K] matrix -----
__global__ void transpose4_kernel(const float* __restrict__ src,
                                  float* __restrict__ dst, int R, int K) {
    int idx = blockIdx.x * blockDim.x + threadIdx.x;
    int total = R * (K >> 2);
    if (idx >= total) return;
    int k4 = idx / R, r = idx - k4 * R;
    float4 v;
    v.x = src[r * K + k4 * 4 + 0];
    v.y = src[r * K + k4 * 4 + 1];
    v.z = src[r * K + k4 * 4 + 2];
    v.w = src[r * K + k4 * 4 + 3];
    ((float4*)dst)[idx] = v;
}

// ---------------- K1c: pack Whh into MFMA B-fragments (bf16 hi/lo) --
__global__ __launch_bounds__(64) void pack_whh_kernel(
    const float* __restrict__ Whh_f, const float* __restrict__ Whh_b,
    unsigned short* __restrict__ Wpk)
{
    const int fid = blockIdx.x;
    const int l   = threadIdx.x;
    const int g   = fid % 3;
    const int kt  = (fid / 3) & 3;
    const int p   = (fid / 12) & 1;
    const int w   = (fid / 24) & 7;
    const int dir = fid / 192;
    const float* W = dir ? Whh_b : Whh_f;
    const int n  = g * HH + w * 16 + (l & 15);
    const int k0 = kt * 32 + (l >> 4) * 8;
    unsigned short* dst = Wpk + (size_t)fid * 512 + l * 8;
    #pragma unroll
    for (int r = 0; r < 8; ++r) {
        float v = W[(size_t)n * HH + k0 + r];
        unsigned short hi = f2bf(v);
        dst[r] = p ? f2bf(v - bf2f(hi)) : hi;
    }
}

// ---------------- K1d: pack Wp into MFMA B-fragments (bf16 hi/lo) ---
__global__ __launch_bounds__(64) void pack_wp_kernel(
    const float* __restrict__ Wp, unsigned short* __restrict__ WpPk)
{
    const int fid = blockIdx.x;
    const int l   = threadIdx.x;
    const int nt  = fid & 7;
    const int kt  = (fid >> 3) & 7;
    const int p   = fid >> 6;
    const int n   = nt * 16 + (l & 15);
    const int k0  = kt * 32 + (l >> 4) * 8;
    unsigned short* dst = WpPk + (size_t)fid * 512 + l * 8;
    #pragma unroll
    for (int r = 0; r < 8; ++r) {
        float v = Wp[(size_t)n * D2H + k0 + r];
        unsigned short hi = f2bf(v);
        dst[r] = p ? f2bf(v - bf2f(hi)) : hi;
    }
}

// ---------------- K1e: pack Wih into MFMA B-fragments (bf16 hi/lo) --
__global__ __launch_bounds__(64) void pack_wih_kernel(
    const float* __restrict__ Wih_f, const float* __restrict__ Wih_b,
    unsigned short* __restrict__ WihPk)
{
    const int fid = blockIdx.x;
    const int l   = threadIdx.x;
    const int nt  = fid % 48;
    const int kt  = (fid / 48) % 7;
    const int p   = fid / 336;
    const int n   = nt * 16 + (l & 15);
    const int k0  = kt * 32 + (l >> 4) * 8;
    const float* W = (n < G3) ? Wih_f : Wih_b;
    const int nl   = (n < G3) ? n : n - G3;
    unsigned short* dst = WihPk + (size_t)fid * 512 + l * 8;
    #pragma unroll
    for (int r = 0; r < 8; ++r) {
        const int k = k0 + r;
        float v = (k < EE) ? W[(size_t)nl * EE + k] : 0.f;
        unsigned short hi = f2bf(v);
        dst[r] = p ? f2bf(v - bf2f(hi)) : hi;
    }
}

// ---------------- K1': PE table via MFMA (Plan C) -------------------
// r16-optimal config (M=64, B hi+lo, acc[4][2]): measured ~64us.
__global__ __launch_bounds__(512) void pe_mfma_kernel(
    const float* __restrict__ emb,
    const unsigned short* __restrict__ WihPk,
    const float* __restrict__ bih_f, const float* __restrict__ bih_b,
    unsigned short* __restrict__ PE)
{
    __shared__ unsigned short ahi[64][264];   // 33.8 KB
    const int b0 = blockIdx.x * 64;
    const int t  = threadIdx.x;
    const int w  = t >> 6, ln = t & 63;       // 8 waves
    for (int idx = t; idx < 64 * 56; idx += 512) {
        const int r = idx / 56, q = idx - r * 56;
        const int row = b0 + r;
        float4 v = make_float4(0.f, 0.f, 0.f, 0.f);
        if (row < VV && q < 50)
            v = *(const float4*)(emb + (size_t)row * EE + q * 4);
        ushort4 h4;
        #pragma unroll
        for (int m = 0; m < 4; ++m)
            (&h4.x)[m] = f2bf((&v.x)[m]);
        *(ushort4*)&ahi[r][q * 4] = h4;
    }
    __syncthreads();
    const int sa = ln & 15, ka = (ln >> 4) * 8;
    const int rb = (ln >> 4) * 4;
    #pragma unroll
    for (int it = 0; it < 3; ++it) {
        const int ntb = it * 16 + w * 2;      // this wave's first n-tile (0..47)
        f32x4 acc[4][2];
        #pragma unroll
        for (int mt = 0; mt < 4; ++mt)
            #pragma unroll
            for (int n2 = 0; n2 < 2; ++n2)
                acc[mt][n2] = (f32x4){0.f, 0.f, 0.f, 0.f};
        #pragma unroll
        for (int kt = 0; kt < 7; ++kt) {
            short8v ah[4];
            #pragma unroll
            for (int mt = 0; mt < 4; ++mt)
                ah[mt] = *(const short8v*)&ahi[mt * 16 + sa][kt * 32 + ka];
            const unsigned short* bb = WihPk + ((size_t)(kt * 48 + ntb)) * 512 + (size_t)ln * 8;
            short8v bh0 = *(const short8v*)(bb);
            short8v bh1 = *(const short8v*)(bb + 512);
            short8v bl0 = *(const short8v*)(bb + (size_t)336 * 512);
            short8v bl1 = *(const short8v*)(bb + (size_t)336 * 512 + 512);
            #pragma unroll
            for (int mt = 0; mt < 4; ++mt) {
                acc[mt][0] = __builtin_amdgcn_mfma_f32_16x16x32_bf16(ah[mt], bh0, acc[mt][0], 0, 0, 0);
                acc[mt][0] = __builtin_amdgcn_mfma_f32_16x16x32_bf16(ah[mt], bl0, acc[mt][0], 0, 0, 0);
                acc[mt][1] = __builtin_amdgcn_mfma_f32_16x16x32_bf16(ah[mt], bh1, acc[mt][1], 0, 0, 0);
                acc[mt][1] = __builtin_amdgcn_mfma_f32_16x16x32_bf16(ah[mt], bl1, acc[mt][1], 0, 0, 0);
            }
        }
        #pragma unroll
        for (int n2 = 0; n2 < 2; ++n2) {
            const int col = (ntb + n2) * 16 + (ln & 15);
            const float bias = (col < G3) ? bih_f[col] : bih_b[col - G3];
            #pragma unroll
            for (int mt = 0; mt < 4; ++mt) {
                #pragma unroll
                for (int reg = 0; reg < 4; ++reg) {
                    const int row = b0 + mt * 16 + rb + reg;
                    if (row < VV)
                        stc(&PE[(size_t)row * PEW + col], acc[mt][n2][reg] + bias);
                }
            }
        }
    }
}

// ---------------- K2: bidirectional GRU recurrence (MFMA) -----------
// r23: 2-step unrolled loop, alternating x register buffers (no copy).
// The old per-step `xr=xrn` copy forced a vmcnt wait on prefetch loads
// INTRA-step (~500cy after issue vs ~900cy HBM latency on the 76.8MB
// PE table) — a ~400cy stall/step. Alternating buffers move the wait
// a full step (~2900cy) after issue.
#define GRU_STEP(STEP, CUR, NXT, XU_r, XU_z, XU_n, XP_r, XP_z, XP_n)           \
  {                                                                            \
    const int lseq = dir ? (LL - 1 - (STEP)) : (STEP);                         \
    short8v ah[4];                                                             \
    _Pragma("unroll")                                                          \
    for (int kt = 0; kt < 4; ++kt)                                             \
      ah[kt] = *(const short8v*)&hh[CUR][sa][kt * 32 + ka];                    \
    {                                                                          \
      int lq = dir ? (LL - 2 - (STEP)) : ((STEP) + 1);                         \
      lq = lq < 0 ? 0 : (lq > LL - 1 ? LL - 1 : lq);                           \
      _Pragma("unroll")                                                        \
      for (int r = 0; r < 4; ++r) {                                            \
        const int tok = xw[(b0 + sb + r) * LL + lq];                           \
        const TPE* pp = PE + (size_t)tok * PEW + peBase + j;                   \
        XP_r[r] = ldc(pp); XP_z[r] = ldc(pp + HH); XP_n[r] = ldc(pp + 2 * HH);\
      }                                                                        \
    }                                                                          \
    f32x4 aR = {0.f,0.f,0.f,0.f}, aZ = {0.f,0.f,0.f,0.f}, aN = {0.f,0.f,0.f,0.f};\
    _Pragma("unroll")                                                          \
    for (int kt = 0; kt < 4; ++kt) {                                           \
      aR = __builtin_amdgcn_mfma_f32_16x16x32_bf16(ah[kt], wb[kt][0], aR, 0, 0, 0);\
      aZ = __builtin_amdgcn_mfma_f32_16x16x32_bf16(ah[kt], wb[kt][1], aZ, 0, 0, 0);\
      aN = __builtin_amdgcn_mfma_f32_16x16x32_bf16(ah[kt], wb[kt][2], aN, 0, 0, 0);\
    }                                                                          \
    _Pragma("unroll")                                                          \
    for (int r = 0; r < 4; ++r) {                                              \
      const int s = sb + r;                                                    \
      const float rr = fast_sigmoid(XU_r[r] + aR[r] + br);                     \
      const float zz = fast_sigmoid(XU_z[r] + aZ[r] + bz);                     \
      const float nn = fast_tanh(XU_n[r] + rr * (aN[r] + bn_));                \
      const float h  = (1.f - zz) * nn + zz * hprev[r];                        \
      hprev[r] = h;                                                            \
      hh[NXT][s][j] = f2bf(h);                                                 \
      stc(&out[((size_t)(b0 + s) * LL + lseq) * D2H + dir * HH + j],           \
          (lseq < lens_r[r]) ? h : 0.f);                                       \
    }                                                                          \
    __builtin_amdgcn_sched_barrier(0);                                         \
    asm volatile("s_waitcnt lgkmcnt(0)" ::: "memory");                         \
    __builtin_amdgcn_s_barrier();                                              \
    __builtin_amdgcn_sched_barrier(0);                                         \
  }

template <typename TPE, typename TOUT>
__global__ __launch_bounds__(512, 2) void gru_kernel(
    const int* __restrict__ xw, const int* __restrict__ lens,
    const TPE* __restrict__ PE,
    const unsigned short* __restrict__ Wpk,
    const float* __restrict__ bhh_f, const float* __restrict__ bhh_b,
    TOUT* __restrict__ out)
{
    const int dir = blockIdx.x >> 7;
    const int b0  = (blockIdx.x & 127) * 16;
    const float* bhh = dir ? bhh_b : bhh_f;
    const int t = threadIdx.x;
    const int w = t >> 6;
    const int l = t & 63;
    const int j  = w * 16 + (l & 15);
    const int sb = (l >> 4) * 4;
    const int sa = l & 15;
    const int ka = (l >> 4) * 8;
    __shared__ unsigned short hh[2][16][136];

    short8v wb[4][3];   // hi-only fragments
    #pragma unroll
    for (int kt = 0; kt < 4; ++kt)
        #pragma unroll
        for (int g = 0; g < 3; ++g) {
            const size_t fid = (size_t)(dir * 192 + w * 24 + kt * 3 + g); // p=0
            wb[kt][g] = *(const short8v*)(Wpk + fid * 512 + (size_t)l * 8);
        }
    for (int i = t; i < 16 * 136; i += 512)
        ((unsigned short*)hh[0])[i] = 0;
    const float br  = bhh[j], bz = bhh[HH + j], bn_ = bhh[2 * HH + j];
    int lens_r[4];
    #pragma unroll
    for (int r = 0; r < 4; ++r) lens_r[r] = lens[b0 + sb + r];
    const int peBase = dir * G3;
    float hprev[4] = {0.f, 0.f, 0.f, 0.f};
    float xA_r[4], xA_z[4], xA_n[4], xB_r[4], xB_z[4], xB_n[4];
    {
        const int lseq = dir ? (LL - 1) : 0;
        #pragma unroll
        for (int r = 0; r < 4; ++r) {
            const int tok = xw[(b0 + sb + r) * LL + lseq];
            const TPE* pp = PE + (size_t)tok * PEW + peBase + j;
            xA_r[r] = ldc(pp); xA_z[r] = ldc(pp + HH); xA_n[r] = ldc(pp + 2 * HH);
        }
    }
    __syncthreads();

    for (int pair = 0; pair < LL / 2; ++pair) {
        const int s0 = 2 * pair;
        // even step: h in hh[0], write hh[1]; use xA, prefetch -> xB
        GRU_STEP(s0,     0, 1, xA_r, xA_z, xA_n, xB_r, xB_z, xB_n);
        // odd step: h in hh[1], write hh[0]; use xB, prefetch -> xA
        GRU_STEP(s0 + 1, 1, 0, xB_r, xB_z, xB_n, xA_r, xA_z, xA_n);
    }
}
#undef GRU_STEP

// ---------------- K3: projection GEMM + BN stats (fp32, Plan A) -----
template <typename TOUT>
__global__ __launch_bounds__(256) void proj_kernel(
    const TOUT* __restrict__ out, const float* __restrict__ WpT4,
    const float* __restrict__ bp,
    float* __restrict__ proj, float* __restrict__ stats)
{
    __shared__ float outs[32][D2H];
    __shared__ float red[2][4];
    const int b0 = blockIdx.x * 32;
    const int l  = blockIdx.y;
    const int t  = threadIdx.x;
    for (int idx = t; idx < 32 * (D2H / 4); idx += 256) {
        int r = idx >> 6, c4 = idx & 63;
        float4 v = ld4(out + ((size_t)(b0 + r) * LL + l) * D2H + c4 * 4);
        *((float4*)&outs[r][c4 * 4]) = v;
    }
    __syncthreads();
    const int tr = t >> 5;
    const int tc = t & 31;
    float acc[4][4] = {};
    for (int k4 = 0; k4 < D2H / 4; ++k4) {
        float4 w[4];
        #pragma unroll
        for (int jj = 0; jj < 4; ++jj)
            w[jj] = ((const float4*)WpT4)[k4 * CDIM + tc * 4 + jj];
        #pragma unroll
        for (int i = 0; i < 4; ++i) {
            float4 a = *((const float4*)&outs[tr * 4 + i][k4 * 4]);
            #pragma unroll
            for (int jj = 0; jj < 4; ++jj) {
                acc[i][jj] = fmaf(a.x, w[jj].x, acc[i][jj]);
                acc[i][jj] = fmaf(a.y, w[jj].y, acc[i][jj]);
                acc[i][jj] = fmaf(a.z, w[jj].z, acc[i][jj]);
                acc[i][jj] = fmaf(a.w, w[jj].w, acc[i][jj]);
            }
        }
    }
    float s1 = 0.f, s2 = 0.f;
    #pragma unroll
    for (int i = 0; i < 4; ++i) {
        int b = b0 + tr * 4 + i;
        float4 pv;
        #pragma unroll
        for (int jj = 0; jj < 4; ++jj) {
            float v = acc[i][jj] + bp[tc * 4 + jj];
            (&pv.x)[jj] = v;
            s1 += v; s2 += v * v;
        }
        *((float4*)(proj + ((size_t)b * LL + l) * CDIM + tc * 4)) = pv;
    }
    #pragma unroll
    for (int off = 32; off > 0; off >>= 1) {
        s1 += __shfl_down(s1, off);
        s2 += __shfl_down(s2, off);
    }
    const int lane = t & 63, wv = t >> 6;
    if (lane == 0) { red[0][wv] = s1; red[1][wv] = s2; }
    __syncthreads();
    if (t == 0) {
        atomicAdd(&stats[l],      red[0][0] + red[0][1] + red[0][2] + red[0][3]);
        atomicAdd(&stats[LL + l], red[1][0] + red[1][1] + red[1][2] + red[1][3]);
    }
}

// ---------------- K3': projection via MFMA (bf16 out) + BN stats ----
__global__ __launch_bounds__(512) void proj_mfma_kernel(
    const unsigned short* __restrict__ out, const unsigned short* __restrict__ WpPk,
    const float* __restrict__ bp,
    float* __restrict__ proj, float* __restrict__ stats)
{
    __shared__ unsigned short outs[64][264];   // 33.8 KB
    __shared__ float red[2][8];
    const int b0 = blockIdx.x * 64;
    const int l  = blockIdx.y;
    const int t  = threadIdx.x;
    const int w  = t >> 6, ln = t & 63;        // 8 waves, wave w owns n-tile w
    for (int idx = t; idx < 64 * 32; idx += 512) {
        const int r = idx >> 5, c8 = idx & 31;
        *(short8v*)&outs[r][c8 * 8] =
            *(const short8v*)(out + ((size_t)(b0 + r) * LL + l) * D2H + c8 * 8);
    }
    __syncthreads();
    const int sa = ln & 15, ka = (ln >> 4) * 8;
    f32x4 acc[4];
    #pragma unroll
    for (int mt = 0; mt < 4; ++mt) acc[mt] = (f32x4){0.f, 0.f, 0.f, 0.f};
    #pragma unroll
    for (int kt = 0; kt < 8; ++kt) {
        short8v a[4];
        #pragma unroll
        for (int mt = 0; mt < 4; ++mt)
            a[mt] = *(const short8v*)&outs[mt * 16 + sa][kt * 32 + ka];
        const unsigned short* bbase = WpPk + ((size_t)kt * 8 + w) * 512 + (size_t)ln * 8;
        short8v bh = *(const short8v*)(bbase);
        #pragma unroll
        for (int mt = 0; mt < 4; ++mt)
            acc[mt] = __builtin_amdgcn_mfma_f32_16x16x32_bf16(a[mt], bh, acc[mt], 0, 0, 0);
    }
    float s1 = 0.f, s2 = 0.f;
    const int rb = (ln >> 4) * 4;
    const int col = w * 16 + (ln & 15);
    const float bpv = bp[col];
    #pragma unroll
    for (int mt = 0; mt < 4; ++mt) {
        #pragma unroll
        for (int reg = 0; reg < 4; ++reg) {
            const int row = b0 + mt * 16 + rb + reg;
            const float v = acc[mt][reg] + bpv;
            proj[((size_t)row * LL + l) * CDIM + col] = v;
            s1 += v; s2 += v * v;
        }
    }
    #pragma unroll
    for (int off = 32; off > 0; off >>= 1) {
        s1 += __shfl_down(s1, off);
        s2 += __shfl_down(s2, off);
    }
    if (ln == 0) { red[0][w] = s1; red[1][w] = s2; }
    __syncthreads();
    if (t == 0) {
        float r1 = 0.f, r2 = 0.f;
        #pragma unroll
        for (int i = 0; i < 8; ++i) { r1 += red[0][i]; r2 += red[1][i]; }
        atomicAdd(&stats[l], r1);
        atomicAdd(&stats[LL + l], r2);
    }
}

// ---------------- K4: BN apply + relu + dot with ctx ----------------
__global__ __launch_bounds__(256) void logits_kernel(
    const float* __restrict__ proj, const float* __restrict__ stats,
    const float* __restrict__ gamma, const float* __restrict__ beta,
    const float* __restrict__ ctx, float* __restrict__ logits)
{
    const int idx  = blockIdx.x * 4 + (threadIdx.x >> 6);
    const int lane = threadIdx.x & 63;
    const int b = idx >> 6, l = idx & 63;
    const float invN = 1.f / (float)(BB * CDIM);
    const float mean = stats[l] * invN;
    const float var  = stats[LL + l] * invN - mean * mean;
    const float inv  = rsqrtf(var + EPSV);
    const float g = gamma[l], be = beta[l];
    const float2 p = ((const float2*)(proj + ((size_t)b * LL + l) * CDIM))[lane];
    const float2 c = ((const float2*)ctx)[lane];
    float v0 = fmaxf((p.x - mean) * inv * g + be, 0.f);
    float v1 = fmaxf((p.y - mean) * inv * g + be, 0.f);
    float s = v0 * c.x + v1 * c.y;
    #pragma unroll
    for (int off = 32; off > 0; off >>= 1) s += __shfl_down(s, off);
    if (lane == 0) logits[idx] = s;
}

// ---------------- K5: softmax over L + weighted sum -----------------
template <typename TOUT>
__global__ __launch_bounds__(256) void att_out_kernel(
    const TOUT* __restrict__ out, const float* __restrict__ logits,
    float* __restrict__ y)
{
    const int b = blockIdx.x;
    const int t = threadIdx.x;
    __shared__ float att[LL];
    if (t < 64) {
        float v = logits[b * LL + t];
        float m = v;
        #pragma unroll
        for (int off = 32; off > 0; off >>= 1) m = fmaxf(m, __shfl_xor(m, off));
        float e = __expf(v - m);
        float ssum = e;
        #pragma unroll
        for (int off = 32; off > 0; off >>= 1) ssum += __shfl_xor(ssum, off);
        att[t] = e / ssum;
    }
    __syncthreads();
    float acc = 0.f;
    const TOUT* ob = out + (size_t)b * LL * D2H + t;
    #pragma unroll
    for (int l = 0; l < LL; ++l) acc = fmaf(ldc(ob + (size_t)l * D2H), att[l], acc);
    y[b * D2H + t] = acc;
}

extern "C" void kernel_launch(void* const* d_in, const int* in_sizes, int n_in,
                              void* d_out, int out_size, void* d_ws, size_t ws_size,
                              hipStream_t stream) {
    const int*   xw     = (const int*)d_in[0];
    const int*   lens   = (const int*)d_in[2];
    const float* emb    = (const float*)d_in[3];
    const float* Wih_f  = (const float*)d_in[4];
    const float* Whh_f  = (const float*)d_in[5];
    const float* bih_f  = (const float*)d_in[6];
    const float* bhh_f  = (const float*)d_in[7];
    const float* Wih_b  = (const float*)d_in[8];
    const float* Whh_b  = (const float*)d_in[9];
    const float* bih_b  = (const float*)d_in[10];
    const float* bhh_b  = (const float*)d_in[11];
    const float* Wp     = (const float*)d_in[12];
    const float* bp     = (const float*)d_in[13];
    const float* gamma  = (const float*)d_in[14];
    const float* beta   = (const float*)d_in[15];
    const float* ctx    = (const float*)d_in[16];
    float* y = (float*)d_out;

    char* base = (char*)d_ws;
    size_t off = 0;
    auto alloc = [&](size_t bytes) -> void* {
        void* p = base + off; off += (bytes + 255) & ~(size_t)255; return p;
    };
    float* WpT4  = (float*)alloc((size_t)CDIM * D2H * 4);
    float* stats = (float*)alloc(2 * LL * 4);
    float* logit = (float*)alloc((size_t)BB * LL * 4);
    unsigned short* Wpk   = (unsigned short*)alloc((size_t)384 * 512 * 2);  // Whh frags
    unsigned short* WpPk  = (unsigned short*)alloc((size_t)128 * 512 * 2);  // Wp frags
    unsigned short* WihPk = (unsigned short*)alloc((size_t)672 * 512 * 2);  // Wih frags
    const size_t extras = off;
    const size_t peB_A  = (size_t)VV * PEW * 4;
    const size_t outB_A = (size_t)BB * LL * D2H * 4;
    const size_t needA  = extras + peB_A + outB_A + 4096;
    const bool planA = ws_size >= needA;

    zero_stats_kernel<<<1, 128, 0, stream>>>(stats);
    pack_whh_kernel<<<384, 64, 0, stream>>>(Whh_f, Whh_b, Wpk);

    if (planA) {
        transpose4_kernel<<<(CDIM * D2H / 4 + 255) / 256, 256, 0, stream>>>(Wp, WpT4, CDIM, D2H);
        float* PE   = (float*)alloc(peB_A);
        float* outb = (float*)alloc(outB_A);
        float* proj = (float*)PE;   // alias: PE dead after gru_kernel
        pe_kernel<float><<<dim3((VV + 127) / 128, PEW / 128), 256, 0, stream>>>(
            emb, Wih_f, bih_f, Wih_b, bih_b, PE);
        gru_kernel<float, float><<<256, 512, 0, stream>>>(
            xw, lens, PE, Wpk, bhh_f, bhh_b, outb);
        proj_kernel<float><<<dim3(BB / 32, LL), 256, 0, stream>>>(outb, WpT4, bp, proj, stats);
        logits_kernel<<<BB * LL / 4, 256, 0, stream>>>(proj, stats, gamma, beta, ctx, logit);
        att_out_kernel<float><<<BB, 256, 0, stream>>>(outb, logit, y);
    } else {
        pack_wp_kernel<<<128, 64, 0, stream>>>(Wp, WpPk);
        pack_wih_kernel<<<672, 64, 0, stream>>>(Wih_f, Wih_b, WihPk);
        unsigned short* PE   = (unsigned short*)alloc((size_t)VV * PEW * 2);
        unsigned short* outb = (unsigned short*)alloc((size_t)BB * LL * D2H * 2);
        float* proj = (float*)PE;   // alias: 67MB fp32 <= 76.8MB bf16 PE region
        pe_mfma_kernel<<<(VV + 63) / 64, 512, 0, stream>>>(
            emb, WihPk, bih_f, bih_b, PE);
        gru_kernel<unsigned short, unsigned short><<<256, 512, 0, stream>>>(
            xw, lens, PE, Wpk, bhh_f, bhh_b, outb);
        proj_mfma_kernel<<<dim3(BB / 64, LL), 512, 0, stream>>>(outb, WpPk, bp, proj, stats);
        logits_kernel<<<BB * LL / 4, 256, 0, stream>>>(proj, stats, gamma, beta, ctx, logit);
        att_out_kernel<unsigned short><<<BB, 256, 0, stream>>>(outb, logit, y);
    }
}

// Round 24
// 184.580 us; speedup vs baseline: 1.4960x; 1.0927x over previous
//
#include <hip/hip_runtime.h>
#include <math.h>

#define BB 2048
#define LL 64
#define EE 200
#define HH 128
#define CDIM 128
#define VV 50000
#define G3 384    // 3H
#define PEW 768   // 2*3H
#define D2H 256   // 2H
#define EPSV 1e-5f

typedef __attribute__((ext_vector_type(8))) short short8v;
typedef __attribute__((ext_vector_type(4))) float f32x4;

__device__ __forceinline__ float fast_sigmoid(float v) {
    return __builtin_amdgcn_rcpf(1.f + __expf(-v));
}
__device__ __forceinline__ float fast_tanh(float a) {
    float e = __expf(-2.f * fabsf(a));
    float m = (1.f - e) * __builtin_amdgcn_rcpf(1.f + e);
    return copysignf(m, a);
}

// ---- bf16 (raw ushort) <-> f32 helpers; storage-dtype overloads ----
__device__ __forceinline__ float bf2f(unsigned short u) {
    union { unsigned int i; float f; } c; c.i = ((unsigned int)u) << 16; return c.f;
}
__device__ __forceinline__ unsigned short f2bf(float f) {
    union { float f; unsigned int i; } c; c.f = f;
    unsigned int r = c.i + 0x7FFF + ((c.i >> 16) & 1);   // round-nearest-even
    return (unsigned short)(r >> 16);
}
__device__ __forceinline__ float ldc(const float* p) { return *p; }
__device__ __forceinline__ float ldc(const unsigned short* p) { return bf2f(*p); }
__device__ __forceinline__ void stc(float* p, float v) { *p = v; }
__device__ __forceinline__ void stc(unsigned short* p, float v) { *p = f2bf(v); }
__device__ __forceinline__ float4 ld4(const float* p) { return *(const float4*)p; }
__device__ __forceinline__ float4 ld4(const unsigned short* p) {
    ushort4 u = *(const ushort4*)p;
    return make_float4(bf2f(u.x), bf2f(u.y), bf2f(u.z), bf2f(u.w));
}

// ---------------- K0: zero the BN stats accumulators ----------------
__global__ void zero_stats_kernel(float* __restrict__ stats) {
    if (threadIdx.x < 2 * LL) stats[threadIdx.x] = 0.f;
}

// ---------------- K1: projected-embedding table (fp32, Plan A) ------
template <typename T>
__global__ __launch_bounds__(256) void pe_kernel(
    const float* __restrict__ emb,
    const float* __restrict__ Wih_f, const float* __restrict__ bih_f,
    const float* __restrict__ Wih_b, const float* __restrict__ bih_b,
    T* __restrict__ PE)
{
    __shared__ float As[8][136];
    __shared__ float Bs[8][136];
    const int mb = blockIdx.x * 128;
    const int nb = blockIdx.y * 128;
    const float* W  = (nb < G3) ? Wih_f : Wih_b;
    const float* bi = (nb < G3) ? bih_f : bih_b;
    const int nloc  = (nb < G3) ? nb : nb - G3;
    const int t  = threadIdx.x;
    const int tr = t >> 4, tc = t & 15;
    const int r  = t >> 1, q = t & 1;
    float acc[8][8] = {};
    for (int k0 = 0; k0 < EE; k0 += 8) {
        float4 av, bv;
        const int arow = mb + r;
        if (arow < VV) av = *(const float4*)(emb + (size_t)arow * EE + k0 + q * 4);
        else           av = make_float4(0.f, 0.f, 0.f, 0.f);
        bv = *(const float4*)(W + (size_t)(nloc + r) * EE + k0 + q * 4);
        __syncthreads();
        #pragma unroll
        for (int m = 0; m < 4; ++m) {
            As[q * 4 + m][r] = (&av.x)[m];
            Bs[q * 4 + m][r] = (&bv.x)[m];
        }
        __syncthreads();
        #pragma unroll
        for (int k = 0; k < 8; ++k) {
            float4 a0 = *(const float4*)&As[k][tr * 4];
            float4 a1 = *(const float4*)&As[k][64 + tr * 4];
            float4 b0 = *(const float4*)&Bs[k][tc * 4];
            float4 b1 = *(const float4*)&Bs[k][64 + tc * 4];
            float a8[8] = {a0.x,a0.y,a0.z,a0.w,a1.x,a1.y,a1.z,a1.w};
            float b8[8] = {b0.x,b0.y,b0.z,b0.w,b1.x,b1.y,b1.z,b1.w};
            #pragma unroll
            for (int i = 0; i < 8; ++i)
                #pragma unroll
                for (int j = 0; j < 8; ++j)
                    acc[i][j] = fmaf(a8[i], b8[j], acc[i][j]);
        }
    }
    #pragma unroll
    for (int i = 0; i < 8; ++i) {
        const int rl  = (i < 4) ? (tr * 4 + i) : (64 + tr * 4 + i - 4);
        const int row = mb + rl;
        if (row >= VV) continue;
        #pragma unroll
        for (int j = 0; j < 8; ++j) {
            const int cl = (j < 4) ? (tc * 4 + j) : (64 + tc * 4 + j - 4);
            stc(&PE[(size_t)row * PEW + nb + cl], acc[i][j] + bi[nloc + cl]);
        }
    }
}

// ---------------- K1b: k-major float4 repack of a [R][K] matrix -----
__global__ void transpose4_kernel(const float* __restrict__ src,
                                  float* __restrict__ dst, int R, int K) {
    int idx = blockIdx.x * blockDim.x + threadIdx.x;
    int total = R * (K >> 2);
    if (idx >= total) return;
    int k4 = idx / R, r = idx - k4 * R;
    float4 v;
    v.x = src[r * K + k4 * 4 + 0];
    v.y = src[r * K + k4 * 4 + 1];
    v.z = src[r * K + k4 * 4 + 2];
    v.w = src[r * K + k4 * 4 + 3];
    ((float4*)dst)[idx] = v;
}

// ---------------- K1c: pack Whh into MFMA B-fragments (bf16 hi/lo) --
__global__ __launch_bounds__(64) void pack_whh_kernel(
    const float* __restrict__ Whh_f, const float* __restrict__ Whh_b,
    unsigned short* __restrict__ Wpk)
{
    const int fid = blockIdx.x;
    const int l   = threadIdx.x;
    const int g   = fid % 3;
    const int kt  = (fid / 3) & 3;
    const int p   = (fid / 12) & 1;
    const int w   = (fid / 24) & 7;
    const int dir = fid / 192;
    const float* W = dir ? Whh_b : Whh_f;
    const int n  = g * HH + w * 16 + (l & 15);
    const int k0 = kt * 32 + (l >> 4) * 8;
    unsigned short* dst = Wpk + (size_t)fid * 512 + l * 8;
    #pragma unroll
    for (int r = 0; r < 8; ++r) {
        float v = W[(size_t)n * HH + k0 + r];
        unsigned short hi = f2bf(v);
        dst[r] = p ? f2bf(v - bf2f(hi)) : hi;
    }
}

// ---------------- K-prep (Plan C): all weight packs + stats zero ----
// bid<384: Whh frags | bid<512: Wp frags | bid<1184: Wih frags | 1184: stats
__global__ __launch_bounds__(64) void prep_kernel(
    const float* __restrict__ Whh_f, const float* __restrict__ Whh_b,
    unsigned short* __restrict__ Wpk,
    const float* __restrict__ Wp, unsigned short* __restrict__ WpPk,
    const float* __restrict__ Wih_f, const float* __restrict__ Wih_b,
    unsigned short* __restrict__ WihPk,
    float* __restrict__ stats)
{
    const int bid = blockIdx.x;
    const int l   = threadIdx.x;
    if (bid < 384) {
        const int fid = bid;
        const int g   = fid % 3;
        const int kt  = (fid / 3) & 3;
        const int p   = (fid / 12) & 1;
        const int w   = (fid / 24) & 7;
        const int dir = fid / 192;
        const float* W = dir ? Whh_b : Whh_f;
        const int n  = g * HH + w * 16 + (l & 15);
        const int k0 = kt * 32 + (l >> 4) * 8;
        unsigned short* dst = Wpk + (size_t)fid * 512 + l * 8;
        #pragma unroll
        for (int r = 0; r < 8; ++r) {
            float v = W[(size_t)n * HH + k0 + r];
            unsigned short hi = f2bf(v);
            dst[r] = p ? f2bf(v - bf2f(hi)) : hi;
        }
    } else if (bid < 512) {
        const int fid = bid - 384;
        const int nt  = fid & 7;
        const int kt  = (fid >> 3) & 7;
        const int p   = fid >> 6;
        const int n   = nt * 16 + (l & 15);
        const int k0  = kt * 32 + (l >> 4) * 8;
        unsigned short* dst = WpPk + (size_t)fid * 512 + l * 8;
        #pragma unroll
        for (int r = 0; r < 8; ++r) {
            float v = Wp[(size_t)n * D2H + k0 + r];
            unsigned short hi = f2bf(v);
            dst[r] = p ? f2bf(v - bf2f(hi)) : hi;
        }
    } else if (bid < 1184) {
        const int fid = bid - 512;
        const int nt  = fid % 48;
        const int kt  = (fid / 48) % 7;
        const int p   = fid / 336;
        const int n   = nt * 16 + (l & 15);
        const int k0  = kt * 32 + (l >> 4) * 8;
        const float* W = (n < G3) ? Wih_f : Wih_b;
        const int nl   = (n < G3) ? n : n - G3;
        unsigned short* dst = WihPk + (size_t)fid * 512 + l * 8;
        #pragma unroll
        for (int r = 0; r < 8; ++r) {
            const int k = k0 + r;
            float v = (k < EE) ? W[(size_t)nl * EE + k] : 0.f;
            unsigned short hi = f2bf(v);
            dst[r] = p ? f2bf(v - bf2f(hi)) : hi;
        }
    } else {
        stats[l] = 0.f;
        stats[64 + l] = 0.f;
    }
}

// ---------------- K1': PE table via MFMA (Plan C) -------------------
// r16-optimal config (M=64, B hi+lo, acc[4][2]): measured ~64us.
__global__ __launch_bounds__(512) void pe_mfma_kernel(
    const float* __restrict__ emb,
    const unsigned short* __restrict__ WihPk,
    const float* __restrict__ bih_f, const float* __restrict__ bih_b,
    unsigned short* __restrict__ PE)
{
    __shared__ unsigned short ahi[64][264];   // 33.8 KB
    const int b0 = blockIdx.x * 64;
    const int t  = threadIdx.x;
    const int w  = t >> 6, ln = t & 63;       // 8 waves
    for (int idx = t; idx < 64 * 56; idx += 512) {
        const int r = idx / 56, q = idx - r * 56;
        const int row = b0 + r;
        float4 v = make_float4(0.f, 0.f, 0.f, 0.f);
        if (row < VV && q < 50)
            v = *(const float4*)(emb + (size_t)row * EE + q * 4);
        ushort4 h4;
        #pragma unroll
        for (int m = 0; m < 4; ++m)
            (&h4.x)[m] = f2bf((&v.x)[m]);
        *(ushort4*)&ahi[r][q * 4] = h4;
    }
    __syncthreads();
    const int sa = ln & 15, ka = (ln >> 4) * 8;
    const int rb = (ln >> 4) * 4;
    #pragma unroll
    for (int it = 0; it < 3; ++it) {
        const int ntb = it * 16 + w * 2;      // this wave's first n-tile (0..47)
        f32x4 acc[4][2];
        #pragma unroll
        for (int mt = 0; mt < 4; ++mt)
            #pragma unroll
            for (int n2 = 0; n2 < 2; ++n2)
                acc[mt][n2] = (f32x4){0.f, 0.f, 0.f, 0.f};
        #pragma unroll
        for (int kt = 0; kt < 7; ++kt) {
            short8v ah[4];
            #pragma unroll
            for (int mt = 0; mt < 4; ++mt)
                ah[mt] = *(const short8v*)&ahi[mt * 16 + sa][kt * 32 + ka];
            const unsigned short* bb = WihPk + ((size_t)(kt * 48 + ntb)) * 512 + (size_t)ln * 8;
            short8v bh0 = *(const short8v*)(bb);
            short8v bh1 = *(const short8v*)(bb + 512);
            short8v bl0 = *(const short8v*)(bb + (size_t)336 * 512);
            short8v bl1 = *(const short8v*)(bb + (size_t)336 * 512 + 512);
            #pragma unroll
            for (int mt = 0; mt < 4; ++mt) {
                acc[mt][0] = __builtin_amdgcn_mfma_f32_16x16x32_bf16(ah[mt], bh0, acc[mt][0], 0, 0, 0);
                acc[mt][0] = __builtin_amdgcn_mfma_f32_16x16x32_bf16(ah[mt], bl0, acc[mt][0], 0, 0, 0);
                acc[mt][1] = __builtin_amdgcn_mfma_f32_16x16x32_bf16(ah[mt], bh1, acc[mt][1], 0, 0, 0);
                acc[mt][1] = __builtin_amdgcn_mfma_f32_16x16x32_bf16(ah[mt], bl1, acc[mt][1], 0, 0, 0);
            }
        }
        #pragma unroll
        for (int n2 = 0; n2 < 2; ++n2) {
            const int col = (ntb + n2) * 16 + (ln & 15);
            const float bias = (col < G3) ? bih_f[col] : bih_b[col - G3];
            #pragma unroll
            for (int mt = 0; mt < 4; ++mt) {
                #pragma unroll
                for (int reg = 0; reg < 4; ++reg) {
                    const int row = b0 + mt * 16 + rb + reg;
                    if (row < VV)
                        stc(&PE[(size_t)row * PEW + col], acc[mt][n2][reg] + bias);
                }
            }
        }
    }
}

// ---------------- K2: bidirectional GRU recurrence (MFMA) -----------
// r23-best: 2-step unrolled loop, alternating x register buffers.
#define GRU_STEP(STEP, CUR, NXT, XU_r, XU_z, XU_n, XP_r, XP_z, XP_n)           \
  {                                                                            \
    const int lseq = dir ? (LL - 1 - (STEP)) : (STEP);                         \
    short8v ah[4];                                                             \
    _Pragma("unroll")                                                          \
    for (int kt = 0; kt < 4; ++kt)                                             \
      ah[kt] = *(const short8v*)&hh[CUR][sa][kt * 32 + ka];                    \
    {                                                                          \
      int lq = dir ? (LL - 2 - (STEP)) : ((STEP) + 1);                         \
      lq = lq < 0 ? 0 : (lq > LL - 1 ? LL - 1 : lq);                           \
      _Pragma("unroll")                                                        \
      for (int r = 0; r < 4; ++r) {                                            \
        const int tok = xw[(b0 + sb + r) * LL + lq];                           \
        const TPE* pp = PE + (size_t)tok * PEW + peBase + j;                   \
        XP_r[r] = ldc(pp); XP_z[r] = ldc(pp + HH); XP_n[r] = ldc(pp + 2 * HH);\
      }                                                                        \
    }                                                                          \
    f32x4 aR = {0.f,0.f,0.f,0.f}, aZ = {0.f,0.f,0.f,0.f}, aN = {0.f,0.f,0.f,0.f};\
    _Pragma("unroll")                                                          \
    for (int kt = 0; kt < 4; ++kt) {                                           \
      aR = __builtin_amdgcn_mfma_f32_16x16x32_bf16(ah[kt], wb[kt][0], aR, 0, 0, 0);\
      aZ = __builtin_amdgcn_mfma_f32_16x16x32_bf16(ah[kt], wb[kt][1], aZ, 0, 0, 0);\
      aN = __builtin_amdgcn_mfma_f32_16x16x32_bf16(ah[kt], wb[kt][2], aN, 0, 0, 0);\
    }                                                                          \
    _Pragma("unroll")                                                          \
    for (int r = 0; r < 4; ++r) {                                              \
      const int s = sb + r;                                                    \
      const float rr = fast_sigmoid(XU_r[r] + aR[r] + br);                     \
      const float zz = fast_sigmoid(XU_z[r] + aZ[r] + bz);                     \
      const float nn = fast_tanh(XU_n[r] + rr * (aN[r] + bn_));                \
      const float h  = (1.f - zz) * nn + zz * hprev[r];                        \
      hprev[r] = h;                                                            \
      hh[NXT][s][j] = f2bf(h);                                                 \
      stc(&out[((size_t)(b0 + s) * LL + lseq) * D2H + dir * HH + j],           \
          (lseq < lens_r[r]) ? h : 0.f);                                       \
    }                                                                          \
    __builtin_amdgcn_sched_barrier(0);                                         \
    asm volatile("s_waitcnt lgkmcnt(0)" ::: "memory");                         \
    __builtin_amdgcn_s_barrier();                                              \
    __builtin_amdgcn_sched_barrier(0);                                         \
  }

template <typename TPE, typename TOUT>
__global__ __launch_bounds__(512, 2) void gru_kernel(
    const int* __restrict__ xw, const int* __restrict__ lens,
    const TPE* __restrict__ PE,
    const unsigned short* __restrict__ Wpk,
    const float* __restrict__ bhh_f, const float* __restrict__ bhh_b,
    TOUT* __restrict__ out)
{
    const int dir = blockIdx.x >> 7;
    const int b0  = (blockIdx.x & 127) * 16;
    const float* bhh = dir ? bhh_b : bhh_f;
    const int t = threadIdx.x;
    const int w = t >> 6;
    const int l = t & 63;
    const int j  = w * 16 + (l & 15);
    const int sb = (l >> 4) * 4;
    const int sa = l & 15;
    const int ka = (l >> 4) * 8;
    __shared__ unsigned short hh[2][16][136];

    short8v wb[4][3];   // hi-only fragments
    #pragma unroll
    for (int kt = 0; kt < 4; ++kt)
        #pragma unroll
        for (int g = 0; g < 3; ++g) {
            const size_t fid = (size_t)(dir * 192 + w * 24 + kt * 3 + g); // p=0
            wb[kt][g] = *(const short8v*)(Wpk + fid * 512 + (size_t)l * 8);
        }
    for (int i = t; i < 16 * 136; i += 512)
        ((unsigned short*)hh[0])[i] = 0;
    const float br  = bhh[j], bz = bhh[HH + j], bn_ = bhh[2 * HH + j];
    int lens_r[4];
    #pragma unroll
    for (int r = 0; r < 4; ++r) lens_r[r] = lens[b0 + sb + r];
    const int peBase = dir * G3;
    float hprev[4] = {0.f, 0.f, 0.f, 0.f};
    float xA_r[4], xA_z[4], xA_n[4], xB_r[4], xB_z[4], xB_n[4];
    {
        const int lseq = dir ? (LL - 1) : 0;
        #pragma unroll
        for (int r = 0; r < 4; ++r) {
            const int tok = xw[(b0 + sb + r) * LL + lseq];
            const TPE* pp = PE + (size_t)tok * PEW + peBase + j;
            xA_r[r] = ldc(pp); xA_z[r] = ldc(pp + HH); xA_n[r] = ldc(pp + 2 * HH);
        }
    }
    __syncthreads();

    for (int pair = 0; pair < LL / 2; ++pair) {
        const int s0 = 2 * pair;
        GRU_STEP(s0,     0, 1, xA_r, xA_z, xA_n, xB_r, xB_z, xB_n);
        GRU_STEP(s0 + 1, 1, 0, xB_r, xB_z, xB_n, xA_r, xA_z, xA_n);
    }
}
#undef GRU_STEP

// ---------------- K3: projection GEMM + BN stats (fp32, Plan A) -----
template <typename TOUT>
__global__ __launch_bounds__(256) void proj_kernel(
    const TOUT* __restrict__ out, const float* __restrict__ WpT4,
    const float* __restrict__ bp,
    float* __restrict__ proj, float* __restrict__ stats)
{
    __shared__ float outs[32][D2H];
    __shared__ float red[2][4];
    const int b0 = blockIdx.x * 32;
    const int l  = blockIdx.y;
    const int t  = threadIdx.x;
    for (int idx = t; idx < 32 * (D2H / 4); idx += 256) {
        int r = idx >> 6, c4 = idx & 63;
        float4 v = ld4(out + ((size_t)(b0 + r) * LL + l) * D2H + c4 * 4);
        *((float4*)&outs[r][c4 * 4]) = v;
    }
    __syncthreads();
    const int tr = t >> 5;
    const int tc = t & 31;
    float acc[4][4] = {};
    for (int k4 = 0; k4 < D2H / 4; ++k4) {
        float4 w[4];
        #pragma unroll
        for (int jj = 0; jj < 4; ++jj)
            w[jj] = ((const float4*)WpT4)[k4 * CDIM + tc * 4 + jj];
        #pragma unroll
        for (int i = 0; i < 4; ++i) {
            float4 a = *((const float4*)&outs[tr * 4 + i][k4 * 4]);
            #pragma unroll
            for (int jj = 0; jj < 4; ++jj) {
                acc[i][jj] = fmaf(a.x, w[jj].x, acc[i][jj]);
                acc[i][jj] = fmaf(a.y, w[jj].y, acc[i][jj]);
                acc[i][jj] = fmaf(a.z, w[jj].z, acc[i][jj]);
                acc[i][jj] = fmaf(a.w, w[jj].w, acc[i][jj]);
            }
        }
    }
    float s1 = 0.f, s2 = 0.f;
    #pragma unroll
    for (int i = 0; i < 4; ++i) {
        int b = b0 + tr * 4 + i;
        float4 pv;
        #pragma unroll
        for (int jj = 0; jj < 4; ++jj) {
            float v = acc[i][jj] + bp[tc * 4 + jj];
            (&pv.x)[jj] = v;
            s1 += v; s2 += v * v;
        }
        *((float4*)(proj + ((size_t)b * LL + l) * CDIM + tc * 4)) = pv;
    }
    #pragma unroll
    for (int off = 32; off > 0; off >>= 1) {
        s1 += __shfl_down(s1, off);
        s2 += __shfl_down(s2, off);
    }
    const int lane = t & 63, wv = t >> 6;
    if (lane == 0) { red[0][wv] = s1; red[1][wv] = s2; }
    __syncthreads();
    if (t == 0) {
        atomicAdd(&stats[l],      red[0][0] + red[0][1] + red[0][2] + red[0][3]);
        atomicAdd(&stats[LL + l], red[1][0] + red[1][1] + red[1][2] + red[1][3]);
    }
}

// ---------------- K3': projection via MFMA (bf16 out) + BN stats ----
__global__ __launch_bounds__(512) void proj_mfma_kernel(
    const unsigned short* __restrict__ out, const unsigned short* __restrict__ WpPk,
    const float* __restrict__ bp,
    float* __restrict__ proj, float* __restrict__ stats)
{
    __shared__ unsigned short outs[64][264];   // 33.8 KB
    __shared__ float red[2][8];
    const int b0 = blockIdx.x * 64;
    const int l  = blockIdx.y;
    const int t  = threadIdx.x;
    const int w  = t >> 6, ln = t & 63;        // 8 waves, wave w owns n-tile w
    for (int idx = t; idx < 64 * 32; idx += 512) {
        const int r = idx >> 5, c8 = idx & 31;
        *(short8v*)&outs[r][c8 * 8] =
            *(const short8v*)(out + ((size_t)(b0 + r) * LL + l) * D2H + c8 * 8);
    }
    __syncthreads();
    const int sa = ln & 15, ka = (ln >> 4) * 8;
    f32x4 acc[4];
    #pragma unroll
    for (int mt = 0; mt < 4; ++mt) acc[mt] = (f32x4){0.f, 0.f, 0.f, 0.f};
    #pragma unroll
    for (int kt = 0; kt < 8; ++kt) {
        short8v a[4];
        #pragma unroll
        for (int mt = 0; mt < 4; ++mt)
            a[mt] = *(const short8v*)&outs[mt * 16 + sa][kt * 32 + ka];
        const unsigned short* bbase = WpPk + ((size_t)kt * 8 + w) * 512 + (size_t)ln * 8;
        short8v bh = *(const short8v*)(bbase);
        #pragma unroll
        for (int mt = 0; mt < 4; ++mt)
            acc[mt] = __builtin_amdgcn_mfma_f32_16x16x32_bf16(a[mt], bh, acc[mt], 0, 0, 0);
    }
    float s1 = 0.f, s2 = 0.f;
    const int rb = (ln >> 4) * 4;
    const int col = w * 16 + (ln & 15);
    const float bpv = bp[col];
    #pragma unroll
    for (int mt = 0; mt < 4; ++mt) {
        #pragma unroll
        for (int reg = 0; reg < 4; ++reg) {
            const int row = b0 + mt * 16 + rb + reg;
            const float v = acc[mt][reg] + bpv;
            proj[((size_t)row * LL + l) * CDIM + col] = v;
            s1 += v; s2 += v * v;
        }
    }
    #pragma unroll
    for (int off = 32; off > 0; off >>= 1) {
        s1 += __shfl_down(s1, off);
        s2 += __shfl_down(s2, off);
    }
    if (ln == 0) { red[0][w] = s1; red[1][w] = s2; }
    __syncthreads();
    if (t == 0) {
        float r1 = 0.f, r2 = 0.f;
        #pragma unroll
        for (int i = 0; i < 8; ++i) { r1 += red[0][i]; r2 += red[1][i]; }
        atomicAdd(&stats[l], r1);
        atomicAdd(&stats[LL + l], r2);
    }
}

// ---------------- K4: BN apply + relu + dot with ctx (Plan A) -------
__global__ __launch_bounds__(256) void logits_kernel(
    const float* __restrict__ proj, const float* __restrict__ stats,
    const float* __restrict__ gamma, const float* __restrict__ beta,
    const float* __restrict__ ctx, float* __restrict__ logits)
{
    const int idx  = blockIdx.x * 4 + (threadIdx.x >> 6);
    const int lane = threadIdx.x & 63;
    const int b = idx >> 6, l = idx & 63;
    const float invN = 1.f / (float)(BB * CDIM);
    const float mean = stats[l] * invN;
    const float var  = stats[LL + l] * invN - mean * mean;
    const float inv  = rsqrtf(var + EPSV);
    const float g = gamma[l], be = beta[l];
    const float2 p = ((const float2*)(proj + ((size_t)b * LL + l) * CDIM))[lane];
    const float2 c = ((const float2*)ctx)[lane];
    float v0 = fmaxf((p.x - mean) * inv * g + be, 0.f);
    float v1 = fmaxf((p.y - mean) * inv * g + be, 0.f);
    float s = v0 * c.x + v1 * c.y;
    #pragma unroll
    for (int off = 32; off > 0; off >>= 1) s += __shfl_down(s, off);
    if (lane == 0) logits[idx] = s;
}

// ---------------- K5: softmax over L + weighted sum (Plan A) --------
template <typename TOUT>
__global__ __launch_bounds__(256) void att_out_kernel(
    const TOUT* __restrict__ out, const float* __restrict__ logits,
    float* __restrict__ y)
{
    const int b = blockIdx.x;
    const int t = threadIdx.x;
    __shared__ float att[LL];
    if (t < 64) {
        float v = logits[b * LL + t];
        float m = v;
        #pragma unroll
        for (int off = 32; off > 0; off >>= 1) m = fmaxf(m, __shfl_xor(m, off));
        float e = __expf(v - m);
        float ssum = e;
        #pragma unroll
        for (int off = 32; off > 0; off >>= 1) ssum += __shfl_xor(ssum, off);
        att[t] = e / ssum;
    }
    __syncthreads();
    float acc = 0.f;
    const TOUT* ob = out + (size_t)b * LL * D2H + t;
    #pragma unroll
    for (int l = 0; l < LL; ++l) acc = fmaf(ldc(ob + (size_t)l * D2H), att[l], acc);
    y[b * D2H + t] = acc;
}

// ---------------- K4+K5 fused (Plan C): BN+relu+ctx-dot, softmax, sum
// Block per batch row. Wave wv computes logits for l = wv*16..wv*16+15.
__global__ __launch_bounds__(256) void att_fused_kernel(
    const unsigned short* __restrict__ out, const float* __restrict__ proj,
    const float* __restrict__ stats,
    const float* __restrict__ gamma, const float* __restrict__ beta,
    const float* __restrict__ ctx, float* __restrict__ y)
{
    const int b = blockIdx.x;
    const int t = threadIdx.x;
    const int wv = t >> 6, lane = t & 63;
    __shared__ float att[LL];
    const float invN = 1.f / (float)(BB * CDIM);
    const float2 c = ((const float2*)ctx)[lane];
    #pragma unroll
    for (int li = 0; li < 16; ++li) {
        const int l = wv * 16 + li;
        const float mean = stats[l] * invN;
        const float var  = stats[LL + l] * invN - mean * mean;
        const float inv  = rsqrtf(var + EPSV);
        const float g = gamma[l], be = beta[l];
        const float2 p = ((const float2*)(proj + ((size_t)b * LL + l) * CDIM))[lane];
        float v0 = fmaxf((p.x - mean) * inv * g + be, 0.f);
        float v1 = fmaxf((p.y - mean) * inv * g + be, 0.f);
        float s = v0 * c.x + v1 * c.y;
        #pragma unroll
        for (int off = 32; off > 0; off >>= 1) s += __shfl_down(s, off);
        if (lane == 0) att[l] = s;
    }
    __syncthreads();
    if (t < 64) {
        float v = att[t];
        float m = v;
        #pragma unroll
        for (int off = 32; off > 0; off >>= 1) m = fmaxf(m, __shfl_xor(m, off));
        float e = __expf(v - m);
        float ssum = e;
        #pragma unroll
        for (int off = 32; off > 0; off >>= 1) ssum += __shfl_xor(ssum, off);
        att[t] = e / ssum;
    }
    __syncthreads();
    float acc = 0.f;
    const unsigned short* ob = out + (size_t)b * LL * D2H + t;
    #pragma unroll
    for (int l = 0; l < LL; ++l) acc = fmaf(ldc(ob + (size_t)l * D2H), att[l], acc);
    y[b * D2H + t] = acc;
}

extern "C" void kernel_launch(void* const* d_in, const int* in_sizes, int n_in,
                              void* d_out, int out_size, void* d_ws, size_t ws_size,
                              hipStream_t stream) {
    const int*   xw     = (const int*)d_in[0];
    const int*   lens   = (const int*)d_in[2];
    const float* emb    = (const float*)d_in[3];
    const float* Wih_f  = (const float*)d_in[4];
    const float* Whh_f  = (const float*)d_in[5];
    const float* bih_f  = (const float*)d_in[6];
    const float* bhh_f  = (const float*)d_in[7];
    const float* Wih_b  = (const float*)d_in[8];
    const float* Whh_b  = (const float*)d_in[9];
    const float* bih_b  = (const float*)d_in[10];
    const float* bhh_b  = (const float*)d_in[11];
    const float* Wp     = (const float*)d_in[12];
    const float* bp     = (const float*)d_in[13];
    const float* gamma  = (const float*)d_in[14];
    const float* beta   = (const float*)d_in[15];
    const float* ctx    = (const float*)d_in[16];
    float* y = (float*)d_out;

    char* base = (char*)d_ws;
    size_t off = 0;
    auto alloc = [&](size_t bytes) -> void* {
        void* p = base + off; off += (bytes + 255) & ~(size_t)255; return p;
    };
    float* WpT4  = (float*)alloc((size_t)CDIM * D2H * 4);
    float* stats = (float*)alloc(2 * LL * 4);
    float* logit = (float*)alloc((size_t)BB * LL * 4);
    unsigned short* Wpk   = (unsigned short*)alloc((size_t)384 * 512 * 2);  // Whh frags
    unsigned short* WpPk  = (unsigned short*)alloc((size_t)128 * 512 * 2);  // Wp frags
    unsigned short* WihPk = (unsigned short*)alloc((size_t)672 * 512 * 2);  // Wih frags
    const size_t extras = off;
    const size_t peB_A  = (size_t)VV * PEW * 4;
    const size_t outB_A = (size_t)BB * LL * D2H * 4;
    const size_t needA  = extras + peB_A + outB_A + 4096;
    const bool planA = ws_size >= needA;

    if (planA) {
        zero_stats_kernel<<<1, 128, 0, stream>>>(stats);
        pack_whh_kernel<<<384, 64, 0, stream>>>(Whh_f, Whh_b, Wpk);
        transpose4_kernel<<<(CDIM * D2H / 4 + 255) / 256, 256, 0, stream>>>(Wp, WpT4, CDIM, D2H);
        float* PE   = (float*)alloc(peB_A);
        float* outb = (float*)alloc(outB_A);
        float* proj = (float*)PE;   // alias: PE dead after gru_kernel
        pe_kernel<float><<<dim3((VV + 127) / 128, PEW / 128), 256, 0, stream>>>(
            emb, Wih_f, bih_f, Wih_b, bih_b, PE);
        gru_kernel<float, float><<<256, 512, 0, stream>>>(
            xw, lens, PE, Wpk, bhh_f, bhh_b, outb);
        proj_kernel<float><<<dim3(BB / 32, LL), 256, 0, stream>>>(outb, WpT4, bp, proj, stats);
        logits_kernel<<<BB * LL / 4, 256, 0, stream>>>(proj, stats, gamma, beta, ctx, logit);
        att_out_kernel<float><<<BB, 256, 0, stream>>>(outb, logit, y);
    } else {
        // single prep dispatch: all packs + stats zero
        prep_kernel<<<1185, 64, 0, stream>>>(
            Whh_f, Whh_b, Wpk, Wp, WpPk, Wih_f, Wih_b, WihPk, stats);
        unsigned short* PE   = (unsigned short*)alloc((size_t)VV * PEW * 2);
        unsigned short* outb = (unsigned short*)alloc((size_t)BB * LL * D2H * 2);
        float* proj = (float*)PE;   // alias: 67MB fp32 <= 76.8MB bf16 PE region
        pe_mfma_kernel<<<(VV + 63) / 64, 512, 0, stream>>>(
            emb, WihPk, bih_f, bih_b, PE);
        gru_kernel<unsigned short, unsigned short><<<256, 512, 0, stream>>>(
            xw, lens, PE, Wpk, bhh_f, bhh_b, outb);
        proj_mfma_kernel<<<dim3(BB / 64, LL), 512, 0, stream>>>(outb, WpPk, bp, proj, stats);
        att_fused_kernel<<<BB, 256, 0, stream>>>(outb, proj, stats, gamma, beta, ctx, y);
    }
}